// Round 1
// baseline (468.427 us; speedup 1.0000x reference)
//
#include <hip/hip_runtime.h>
#include <math.h>

#define SB 4
#define SS 4096
#define SD 256
#define SN 16
#define SR 16
#define ROWS 8
#define NROWSB 2048      // 16384 rows / ROWS
#define CH 256           // chunk length for scan
#define NCH 16           // chunks = SS/CH

__device__ __forceinline__ float softplus_f(float x){
    return fmaxf(x, 0.f) + log1pf(expf(-fabsf(x)));
}
__device__ __forceinline__ float silu_f(float x){
    return x / (1.f + expf(-x));
}

// Transpose Wcf/Wcb (used as x @ Wc.T) so the GEMM reads coalesced.
__global__ __launch_bounds__(256)
void k_transpose(const float* __restrict__ W0, const float* __restrict__ W1,
                 float* __restrict__ T0, float* __restrict__ T1){
    int blk = blockIdx.x;            // 0..511
    int d = blk & 255; int which = blk >> 8;
    int e = threadIdx.x;
    const float* W = which ? W1 : W0;
    float* T = which ? T1 : T0;
    T[d*SD + e] = W[e*SD + d];
}

// LayerNorm + z1 = xn @ Wp + bp   (8 rows per 256-thread block)
__global__ __launch_bounds__(256)
void k_ln_proj(const float* __restrict__ x, const float* __restrict__ g,
               const float* __restrict__ bln, const float* __restrict__ Wp,
               const float* __restrict__ bp, float* __restrict__ z1){
    __shared__ float xnT[SD*ROWS];
    int row0 = blockIdx.x * ROWS;
    int tid = threadIdx.x; int w = tid >> 6; int lane = tid & 63;
    #pragma unroll
    for (int rep = 0; rep < 2; ++rep){
        int j = w + rep*4;
        int r = row0 + j;
        const float* xr = x + (size_t)r*SD;
        float4 v = *(const float4*)(xr + lane*4);
        float s = v.x + v.y + v.z + v.w;
        #pragma unroll
        for (int off = 32; off; off >>= 1) s += __shfl_xor(s, off, 64);
        float mu = s * (1.f/256.f);
        float d0 = v.x-mu, d1 = v.y-mu, d2 = v.z-mu, d3 = v.w-mu;
        float q = d0*d0 + d1*d1 + d2*d2 + d3*d3;
        #pragma unroll
        for (int off = 32; off; off >>= 1) q += __shfl_xor(q, off, 64);
        float rstd = rsqrtf(q*(1.f/256.f) + 1e-5f);
        int e = lane*4;
        float4 gg = *(const float4*)(g + e);
        float4 bb = *(const float4*)(bln + e);
        xnT[(e+0)*ROWS + j] = d0*rstd*gg.x + bb.x;
        xnT[(e+1)*ROWS + j] = d1*rstd*gg.y + bb.y;
        xnT[(e+2)*ROWS + j] = d2*rstd*gg.z + bb.z;
        xnT[(e+3)*ROWS + j] = d3*rstd*gg.w + bb.w;
    }
    __syncthreads();
    int e = tid;
    float acc[ROWS];
    float bpe = bp[e];
    #pragma unroll
    for (int j = 0; j < ROWS; ++j) acc[j] = bpe;
    for (int d = 0; d < SD; ++d){
        float wv = Wp[d*SD + e];
        const float* xn = &xnT[d*ROWS];
        #pragma unroll
        for (int j = 0; j < ROWS; ++j) acc[j] = fmaf(xn[j], wv, acc[j]);
    }
    #pragma unroll
    for (int j = 0; j < ROWS; ++j) z1[(size_t)(row0+j)*SD + e] = acc[j];
}

// Per-direction pointwise: xc = softplus(z1 @ WcT + bc); dbc = xc @ Wdbc;
// delta = softplus(dt_r @ Wdt + bdt); stores xc, delta, B, C.
__global__ __launch_bounds__(256)
void k_pointwise(const float* __restrict__ z1,
                 const float* __restrict__ WcT0, const float* __restrict__ bc0,
                 const float* __restrict__ Wdbc0, const float* __restrict__ Wdt0, const float* __restrict__ bdt0,
                 const float* __restrict__ WcT1, const float* __restrict__ bc1,
                 const float* __restrict__ Wdbc1, const float* __restrict__ Wdt1, const float* __restrict__ bdt1,
                 float* __restrict__ xcg0, float* __restrict__ dg0, float* __restrict__ Bg0, float* __restrict__ Cg0,
                 float* __restrict__ xcg1, float* __restrict__ dg1, float* __restrict__ Bg1, float* __restrict__ Cg1)
{
    __shared__ float z1T[SD*ROWS];
    __shared__ float xcT[SD*ROWS];
    __shared__ float dbcT[48*ROWS];
    int row0 = blockIdx.x * ROWS;
    int e = threadIdx.x;
    #pragma unroll
    for (int j = 0; j < ROWS; ++j) z1T[e*ROWS + j] = z1[(size_t)(row0+j)*SD + e];
    __syncthreads();
    for (int dir = 0; dir < 2; ++dir){
        const float* WcT  = dir ? WcT1  : WcT0;
        const float* bc   = dir ? bc1   : bc0;
        const float* Wdbc = dir ? Wdbc1 : Wdbc0;
        const float* Wdt  = dir ? Wdt1  : Wdt0;
        const float* bdt  = dir ? bdt1  : bdt0;
        float* xcg = dir ? xcg1 : xcg0;
        float* dg  = dir ? dg1  : dg0;
        float* Bg  = dir ? Bg1  : Bg0;
        float* Cg  = dir ? Cg1  : Cg0;

        float acc[ROWS]; float bce = bc[e];
        #pragma unroll
        for (int j = 0; j < ROWS; ++j) acc[j] = bce;
        for (int d = 0; d < SD; ++d){
            float wv = WcT[d*SD + e];
            #pragma unroll
            for (int j = 0; j < ROWS; ++j) acc[j] = fmaf(z1T[d*ROWS + j], wv, acc[j]);
        }
        #pragma unroll
        for (int j = 0; j < ROWS; ++j){
            float v = softplus_f(acc[j]);
            xcg[(size_t)(row0+j)*SD + e] = v;
            xcT[e*ROWS + j] = v;
        }
        __syncthreads();
        if (e < 48){
            float a2[ROWS];
            #pragma unroll
            for (int j = 0; j < ROWS; ++j) a2[j] = 0.f;
            for (int d = 0; d < SD; ++d){
                float wv = Wdbc[d*48 + e];
                #pragma unroll
                for (int j = 0; j < ROWS; ++j) a2[j] = fmaf(xcT[d*ROWS + j], wv, a2[j]);
            }
            #pragma unroll
            for (int j = 0; j < ROWS; ++j) dbcT[e*ROWS + j] = a2[j];
            if (e >= 16 && e < 32){
                #pragma unroll
                for (int j = 0; j < ROWS; ++j) Bg[(size_t)(row0+j)*SN + (e-16)] = a2[j];
            } else if (e >= 32){
                #pragma unroll
                for (int j = 0; j < ROWS; ++j) Cg[(size_t)(row0+j)*SN + (e-32)] = a2[j];
            }
        }
        __syncthreads();
        float a3[ROWS]; float bde = bdt[e];
        #pragma unroll
        for (int j = 0; j < ROWS; ++j) a3[j] = bde;
        #pragma unroll
        for (int r = 0; r < SR; ++r){
            float wv = Wdt[r*SD + e];
            #pragma unroll
            for (int j = 0; j < ROWS; ++j) a3[j] = fmaf(dbcT[r*ROWS + j], wv, a3[j]);
        }
        #pragma unroll
        for (int j = 0; j < ROWS; ++j) dg[(size_t)(row0+j)*SD + e] = softplus_f(a3[j]);
        __syncthreads();
    }
}

// Chunked two-pass selective scan. Block = (b, dir, 4-channel group), 16 waves,
// wave = chunk of 256 steps. Lane = (local channel ld, state n).
__global__ __launch_bounds__(1024)
void k_scan(const float* __restrict__ xc0, const float* __restrict__ d0,
            const float* __restrict__ B0, const float* __restrict__ C0,
            const float* __restrict__ Al0, const float* __restrict__ Dv0,
            float* __restrict__ y0,
            const float* __restrict__ xc1, const float* __restrict__ d1,
            const float* __restrict__ B1, const float* __restrict__ C1,
            const float* __restrict__ Al1, const float* __restrict__ Dv1,
            float* __restrict__ y1)
{
    __shared__ float s_ap[NCH][64];
    __shared__ float s_h[NCH][64];
    __shared__ float s_hin[NCH][64];
    int blk = blockIdx.x;                 // 512 = 4b * 2dir * 64 groups
    int dg  = blk & 63;
    int dir = (blk >> 6) & 1;
    int b   = blk >> 7;
    const float* xc    = dir ? xc1 : xc0;
    const float* delta = dir ? d1  : d0;
    const float* Bg    = dir ? B1  : B0;
    const float* Cg    = dir ? C1  : C0;
    const float* Alog  = dir ? Al1 : Al0;
    const float* Dv    = dir ? Dv1 : Dv0;
    float* y           = dir ? y1  : y0;

    int tid = threadIdx.x;
    int c = tid >> 6;                     // chunk index = wave
    int lane = tid & 63;
    int ld = lane >> 4; int n = lane & 15;
    int d = dg*4 + ld;
    float A = -expf(Alog[d*SN + n]);
    size_t baseRow = (size_t)b * SS;

    // pass 1: local scan (h_in = 0), track product of a
    float h = 0.f, ap = 1.f;
    for (int i = 0; i < CH; ++i){
        int tau = c*CH + i;
        int t = dir ? (SS-1-tau) : tau;
        size_t row = baseRow + t;
        float dl = delta[row*SD + d];
        float xv = xc[row*SD + d];
        float Bv = Bg[row*SN + n];
        float a = expf(dl * A);
        h = fmaf(a, h, dl*Bv*xv);
        ap *= a;
    }
    s_ap[c][lane] = ap; s_h[c][lane] = h;
    __syncthreads();
    // serial combine across 16 chunks (64 threads, one per lane-slot)
    if (tid < 64){
        float H = 0.f;
        #pragma unroll
        for (int cc = 0; cc < NCH; ++cc){
            s_hin[cc][tid] = H;
            H = s_ap[cc][tid]*H + s_h[cc][tid];
        }
    }
    __syncthreads();
    // pass 2: real scan with correct h_in; emit y
    h = s_hin[c][lane];
    float Dd = Dv[d];
    for (int i = 0; i < CH; ++i){
        int tau = c*CH + i;
        int t = dir ? (SS-1-tau) : tau;
        size_t row = baseRow + t;
        float dl = delta[row*SD + d];
        float xv = xc[row*SD + d];
        float Bv = Bg[row*SN + n];
        float Cv = Cg[row*SN + n];
        float a = expf(dl * A);
        h = fmaf(a, h, dl*Bv*xv);
        float p = h * Cv;
        p += __shfl_xor(p, 1, 16);
        p += __shfl_xor(p, 2, 16);
        p += __shfl_xor(p, 4, 16);
        p += __shfl_xor(p, 8, 16);
        if (n == 0) y[row*SD + d] = p + Dd*xv;
    }
}

// out = (silu(yf) + silu(yb)) * silu(z1) + x
__global__ __launch_bounds__(256)
void k_combine(const float* __restrict__ yf, const float* __restrict__ yb,
               const float* __restrict__ z1, const float* __restrict__ x,
               float* __restrict__ out, int nvec)
{
    int i = blockIdx.x*256 + threadIdx.x;
    if (i < nvec){
        float4 a = ((const float4*)yf)[i];
        float4 bq = ((const float4*)yb)[i];
        float4 zq = ((const float4*)z1)[i];
        float4 xq = ((const float4*)x)[i];
        float4 o;
        o.x = (silu_f(a.x) + silu_f(bq.x)) * silu_f(zq.x) + xq.x;
        o.y = (silu_f(a.y) + silu_f(bq.y)) * silu_f(zq.y) + xq.y;
        o.z = (silu_f(a.z) + silu_f(bq.z)) * silu_f(zq.z) + xq.z;
        o.w = (silu_f(a.w) + silu_f(bq.w)) * silu_f(zq.w) + xq.w;
        ((float4*)out)[i] = o;
    }
}

extern "C" void kernel_launch(void* const* d_in, const int* in_sizes, int n_in,
                              void* d_out, int out_size, void* d_ws, size_t ws_size,
                              hipStream_t stream) {
    const float* x     = (const float*)d_in[0];
    const float* ln_g  = (const float*)d_in[1];
    const float* ln_b  = (const float*)d_in[2];
    const float* Wp    = (const float*)d_in[3];
    const float* bp    = (const float*)d_in[4];
    const float* Wcf   = (const float*)d_in[5];
    const float* bcf   = (const float*)d_in[6];
    const float* Wcb   = (const float*)d_in[7];
    const float* bcb   = (const float*)d_in[8];
    const float* Wdbc_f= (const float*)d_in[9];
    const float* Wdt_f = (const float*)d_in[10];
    const float* bdt_f = (const float*)d_in[11];
    const float* Alog_f= (const float*)d_in[12];
    const float* D_f   = (const float*)d_in[13];
    const float* Wdbc_b= (const float*)d_in[14];
    const float* Wdt_b = (const float*)d_in[15];
    const float* bdt_b = (const float*)d_in[16];
    const float* Alog_b= (const float*)d_in[17];
    const float* D_b   = (const float*)d_in[18];
    float* out = (float*)d_out;

    // workspace layout (floats)
    float* ws = (float*)d_ws;
    const size_t NTOK = (size_t)SB*SS;            // 16384
    const size_t SZ_BD = NTOK*SD;                 // 4,194,304
    const size_t SZ_BN = NTOK*SN;                 // 262,144
    float* z1    = ws;                    size_t off = SZ_BD;
    float* xcg0  = ws + off; off += SZ_BD;
    float* xcg1  = ws + off; off += SZ_BD;
    float* dg0   = ws + off; off += SZ_BD;
    float* dg1   = ws + off; off += SZ_BD;
    float* Bg0   = ws + off; off += SZ_BN;
    float* Bg1   = ws + off; off += SZ_BN;
    float* Cg0   = ws + off; off += SZ_BN;
    float* Cg1   = ws + off; off += SZ_BN;
    float* y0    = ws + off; off += SZ_BD;
    float* y1    = ws + off; off += SZ_BD;
    float* WcfT  = ws + off; off += (size_t)SD*SD;
    float* WcbT  = ws + off; off += (size_t)SD*SD;

    k_transpose<<<512, 256, 0, stream>>>(Wcf, Wcb, WcfT, WcbT);
    k_ln_proj<<<NROWSB, 256, 0, stream>>>(x, ln_g, ln_b, Wp, bp, z1);
    k_pointwise<<<NROWSB, 256, 0, stream>>>(z1,
        WcfT, bcf, Wdbc_f, Wdt_f, bdt_f,
        WcbT, bcb, Wdbc_b, Wdt_b, bdt_b,
        xcg0, dg0, Bg0, Cg0,
        xcg1, dg1, Bg1, Cg1);
    k_scan<<<512, 1024, 0, stream>>>(
        xcg0, dg0, Bg0, Cg0, Alog_f, D_f, y0,
        xcg1, dg1, Bg1, Cg1, Alog_b, D_b, y1);
    k_combine<<<4096, 256, 0, stream>>>(y0, y1, z1, x, out, (int)(SZ_BD/4));
}

// Round 2
// 240.089 us; speedup vs baseline: 1.9511x; 1.9511x over previous
//
#include <hip/hip_runtime.h>
#include <math.h>

#define SB 4
#define SS 4096
#define SD 256
#define SN 16
#define SR 16
#define ROWS 16
#define NRB 1024        // 16384 rows / 16
#define NCH 128         // chunks per (b,dir)
#define CHL 32          // chunk length; NCH*CHL = SS

__device__ __forceinline__ float softplus_f(float x){
    return fmaxf(x, 0.f) + __logf(1.f + __expf(-fabsf(x)));
}
__device__ __forceinline__ float silu_f(float x){
    return x * __builtin_amdgcn_rcpf(1.f + __expf(-x));
}

// Transpose Wcf/Wcb (used as x @ Wc.T) so the conv GEMM reads coalesced.
__global__ __launch_bounds__(256)
void k_transpose(const float* __restrict__ W0, const float* __restrict__ W1,
                 float* __restrict__ T0, float* __restrict__ T1){
    int blk = blockIdx.x;            // 0..511
    int d = blk & 255; int which = blk >> 8;
    int e = threadIdx.x;
    const float* W = which ? W1 : W0;
    float* T = which ? T1 : T0;
    T[d*SD + e] = W[e*SD + d];
}

// LayerNorm + z1 = xn @ Wp + bp.  16 rows/block, 4x4 register tile GEMM.
__global__ __launch_bounds__(256)
void k_ln_proj(const float* __restrict__ x, const float* __restrict__ g,
               const float* __restrict__ bln, const float* __restrict__ Wp,
               const float* __restrict__ bp, float* __restrict__ z1){
    __shared__ float xnT[ROWS][SD];
    int row0 = blockIdx.x * ROWS;
    int tid = threadIdx.x; int w = tid >> 6; int lane = tid & 63;
    #pragma unroll
    for (int rep = 0; rep < 4; ++rep){
        int j = rep*4 + w;
        const float* xr = x + (size_t)(row0 + j)*SD;
        float4 v = *(const float4*)(xr + lane*4);
        float s = v.x + v.y + v.z + v.w;
        #pragma unroll
        for (int off = 32; off; off >>= 1) s += __shfl_xor(s, off, 64);
        float mu = s * (1.f/256.f);
        float d0 = v.x-mu, d1 = v.y-mu, d2 = v.z-mu, d3 = v.w-mu;
        float q = d0*d0 + d1*d1 + d2*d2 + d3*d3;
        #pragma unroll
        for (int off = 32; off; off >>= 1) q += __shfl_xor(q, off, 64);
        float rstd = rsqrtf(q*(1.f/256.f) + 1e-5f);
        float4 gg = *(const float4*)(g + lane*4);
        float4 bb = *(const float4*)(bln + lane*4);
        float4 o;
        o.x = d0*rstd*gg.x + bb.x;
        o.y = d1*rstd*gg.y + bb.y;
        o.z = d2*rstd*gg.z + bb.z;
        o.w = d3*rstd*gg.w + bb.w;
        *(float4*)&xnT[j][lane*4] = o;   // contiguous b128, conflict-free
    }
    __syncthreads();
    int tx = tid & 63; int ty = tid >> 6;       // ty = wave id -> uniform LDS reads
    float4 acc[4];
    float4 bp4 = *(const float4*)(bp + tx*4);
    #pragma unroll
    for (int q = 0; q < 4; ++q) acc[q] = bp4;
    for (int d = 0; d < SD; ++d){
        float4 wv = *(const float4*)(Wp + (size_t)d*SD + tx*4);
        #pragma unroll
        for (int q = 0; q < 4; ++q){
            float a = xnT[ty*4+q][d];           // uniform broadcast
            acc[q].x = fmaf(a, wv.x, acc[q].x);
            acc[q].y = fmaf(a, wv.y, acc[q].y);
            acc[q].z = fmaf(a, wv.z, acc[q].z);
            acc[q].w = fmaf(a, wv.w, acc[q].w);
        }
    }
    #pragma unroll
    for (int q = 0; q < 4; ++q)
        *(float4*)(z1 + (size_t)(row0 + ty*4 + q)*SD + tx*4) = acc[q];
}

// Per-direction pointwise: xc = softplus(z1 @ WcT + bc); dbc = xc @ Wdbc;
// delta = softplus(dt_r @ Wdt + bdt); emits xc, delta, B, C.
__global__ __launch_bounds__(256)
void k_pointwise(const float* __restrict__ z1,
                 const float* __restrict__ WcT0, const float* __restrict__ bc0,
                 const float* __restrict__ Wdbc0, const float* __restrict__ Wdt0, const float* __restrict__ bdt0,
                 const float* __restrict__ WcT1, const float* __restrict__ bc1,
                 const float* __restrict__ Wdbc1, const float* __restrict__ Wdt1, const float* __restrict__ bdt1,
                 float* __restrict__ xcg0, float* __restrict__ dg0, float* __restrict__ Bg0, float* __restrict__ Cg0,
                 float* __restrict__ xcg1, float* __restrict__ dg1, float* __restrict__ Bg1, float* __restrict__ Cg1)
{
    __shared__ float z1T[ROWS][SD];
    __shared__ float xcT[ROWS][SD];
    __shared__ float dbcT[ROWS][49];
    int row0 = blockIdx.x * ROWS;
    int tid = threadIdx.x;
    int tx = tid & 63; int ty = tid >> 6;
    // stage z1 tile: 16 consecutive rows = 16KB contiguous
    {
        const float4* zsrc = (const float4*)(z1 + (size_t)row0*SD);
        float4* zdst = (float4*)&z1T[0][0];
        #pragma unroll
        for (int k = 0; k < 4; ++k) zdst[tid + k*256] = zsrc[tid + k*256];
    }
    __syncthreads();
    for (int dir = 0; dir < 2; ++dir){
        const float* WcT  = dir ? WcT1  : WcT0;
        const float* bc   = dir ? bc1   : bc0;
        const float* Wdbc = dir ? Wdbc1 : Wdbc0;
        const float* Wdt  = dir ? Wdt1  : Wdt0;
        const float* bdt  = dir ? bdt1  : bdt0;
        float* xcg = dir ? xcg1 : xcg0;
        float* dg  = dir ? dg1  : dg0;
        float* Bgp = dir ? Bg1  : Bg0;
        float* Cgp = dir ? Cg1  : Cg0;

        // GEMM: xc = softplus(z1 @ WcT + bc)
        float4 acc[4];
        float4 bc4 = *(const float4*)(bc + tx*4);
        #pragma unroll
        for (int q = 0; q < 4; ++q) acc[q] = bc4;
        for (int d = 0; d < SD; ++d){
            float4 wv = *(const float4*)(WcT + (size_t)d*SD + tx*4);
            #pragma unroll
            for (int q = 0; q < 4; ++q){
                float a = z1T[ty*4+q][d];
                acc[q].x = fmaf(a, wv.x, acc[q].x);
                acc[q].y = fmaf(a, wv.y, acc[q].y);
                acc[q].z = fmaf(a, wv.z, acc[q].z);
                acc[q].w = fmaf(a, wv.w, acc[q].w);
            }
        }
        #pragma unroll
        for (int q = 0; q < 4; ++q){
            float4 o;
            o.x = softplus_f(acc[q].x); o.y = softplus_f(acc[q].y);
            o.z = softplus_f(acc[q].z); o.w = softplus_f(acc[q].w);
            *(float4*)&xcT[ty*4+q][tx*4] = o;
            *(float4*)(xcg + (size_t)(row0 + ty*4 + q)*SD + tx*4) = o;
        }
        __syncthreads();
        // dbc = xc @ Wdbc  (48 cols)
        if (tx < 48){
            float a2[4] = {0.f,0.f,0.f,0.f};
            for (int d = 0; d < SD; ++d){
                float wv = Wdbc[(size_t)d*48 + tx];
                #pragma unroll
                for (int q = 0; q < 4; ++q) a2[q] = fmaf(xcT[ty*4+q][d], wv, a2[q]);
            }
            #pragma unroll
            for (int q = 0; q < 4; ++q) dbcT[ty*4+q][tx] = a2[q];
        }
        __syncthreads();
        // B, C extraction (coalesced: global idx == row0*16 + tid)
        {
            int j = tid >> 4; int n = tid & 15;
            Bgp[(size_t)(row0+j)*SN + n] = dbcT[j][16+n];
            Cgp[(size_t)(row0+j)*SN + n] = dbcT[j][32+n];
        }
        // delta = softplus(dt_r @ Wdt + bdt)
        float4 a3[4];
        float4 bd4 = *(const float4*)(bdt + tx*4);
        #pragma unroll
        for (int q = 0; q < 4; ++q) a3[q] = bd4;
        #pragma unroll
        for (int r = 0; r < SR; ++r){
            float4 wv = *(const float4*)(Wdt + (size_t)r*SD + tx*4);
            #pragma unroll
            for (int q = 0; q < 4; ++q){
                float a = dbcT[ty*4+q][r];
                a3[q].x = fmaf(a, wv.x, a3[q].x);
                a3[q].y = fmaf(a, wv.y, a3[q].y);
                a3[q].z = fmaf(a, wv.z, a3[q].z);
                a3[q].w = fmaf(a, wv.w, a3[q].w);
            }
        }
        #pragma unroll
        for (int q = 0; q < 4; ++q){
            float4 o;
            o.x = softplus_f(a3[q].x); o.y = softplus_f(a3[q].y);
            o.z = softplus_f(a3[q].z); o.w = softplus_f(a3[q].w);
            *(float4*)(dg + (size_t)(row0 + ty*4 + q)*SD + tx*4) = o;
        }
        __syncthreads();   // xcT/dbcT reused by next dir
    }
}

// Scan pass 1: per-chunk h_end + sum(delta). Thread owns one d, 16 states in regs.
__global__ __launch_bounds__(256)
void k_scan_p1(const float* __restrict__ xc0, const float* __restrict__ dg0,
               const float* __restrict__ B0,  const float* __restrict__ Al0,
               const float* __restrict__ xc1, const float* __restrict__ dg1,
               const float* __restrict__ B1,  const float* __restrict__ Al1,
               float* __restrict__ hend, float* __restrict__ sdl)
{
    __shared__ float sB[CHL*SN];
    int blk = blockIdx.x;                 // 1024 = b(4) * dir(2) * c(128)
    int c = blk & (NCH-1); int dir = (blk>>7) & 1; int b = blk>>8;
    const float* xc   = dir ? xc1 : xc0;
    const float* dg   = dir ? dg1 : dg0;
    const float* Bg   = dir ? B1  : B0;
    const float* Alog = dir ? Al1 : Al0;
    int d = threadIdx.x;
    #pragma unroll
    for (int k = 0; k < 2; ++k){
        int li = threadIdx.x + k*256;
        int i = li >> 4, n = li & 15;
        int tau = c*CHL + i;
        int t = dir ? (SS-1-tau) : tau;
        sB[li] = Bg[((size_t)b*SS + t)*SN + n];
    }
    float A[SN];
    #pragma unroll
    for (int k = 0; k < 4; ++k){
        float4 al = *(const float4*)(Alog + d*SN + k*4);
        A[k*4+0] = -__expf(al.x); A[k*4+1] = -__expf(al.y);
        A[k*4+2] = -__expf(al.z); A[k*4+3] = -__expf(al.w);
    }
    __syncthreads();
    int t0 = dir ? (SS-1 - c*CHL) : (c*CHL);
    const float* pd = dg + ((size_t)b*SS + t0)*SD + d;
    const float* px = xc + ((size_t)b*SS + t0)*SD + d;
    int stride = dir ? -SD : SD;
    float h[SN];
    #pragma unroll
    for (int n = 0; n < SN; ++n) h[n] = 0.f;
    float sumdl = 0.f;
    float dl = *pd, xv = *px;
    for (int i = 0; i < CHL; ++i){
        float dlN = 0.f, xvN = 0.f;
        if (i+1 < CHL){ pd += stride; px += stride; dlN = *pd; xvN = *px; }
        sumdl += dl;
        float dlx = dl * xv;
        const float4* b4 = (const float4*)&sB[i*SN];
        #pragma unroll
        for (int k = 0; k < 4; ++k){
            float4 bb = b4[k];
            h[k*4+0] = fmaf(__expf(dl*A[k*4+0]), h[k*4+0], bb.x*dlx);
            h[k*4+1] = fmaf(__expf(dl*A[k*4+1]), h[k*4+1], bb.y*dlx);
            h[k*4+2] = fmaf(__expf(dl*A[k*4+2]), h[k*4+2], bb.z*dlx);
            h[k*4+3] = fmaf(__expf(dl*A[k*4+3]), h[k*4+3], bb.w*dlx);
        }
        dl = dlN; xv = xvN;
    }
    size_t base = (((size_t)(b*2+dir)*NCH + c)*SD + d)*SN;
    #pragma unroll
    for (int k = 0; k < 4; ++k)
        *(float4*)(hend + base + k*4) = make_float4(h[k*4+0],h[k*4+1],h[k*4+2],h[k*4+3]);
    sdl[((size_t)(b*2+dir)*NCH + c)*SD + d] = sumdl;
}

// Chain chunks serially per (b,dir,d,n); in-place turns hend into h_in.
__global__ __launch_bounds__(256)
void k_chain(const float* __restrict__ Al0, const float* __restrict__ Al1,
             float* hend, const float* __restrict__ sdl)
{
    int gidx = blockIdx.x*256 + threadIdx.x;       // 32768
    int n = gidx & 15; int d = (gidx >> 4) & 255; int dirb = gidx >> 12;
    const float* Alog = (dirb & 1) ? Al1 : Al0;
    float A = -__expf(Alog[d*SN + n]);
    float H = 0.f;
    const size_t cs = (size_t)SD*SN;               // 4096
    size_t idx  = (size_t)dirb*NCH*cs + (size_t)d*SN + n;
    size_t sidx = (size_t)dirb*NCH*SD + d;
    float he = hend[idx]; float sd = sdl[sidx];
    for (int cg = 0; cg < NCH; ++cg){
        float heN = 0.f, sdN = 0.f;
        if (cg+1 < NCH){ heN = hend[idx + cs]; sdN = sdl[sidx + SD]; }
        hend[idx] = H;                              // now holds h_in
        H = fmaf(__expf(A*sd), H, he);
        he = heN; sd = sdN; idx += cs; sidx += SD;
    }
}

// Scan pass 2: recompute with h_in, emit y (aliases the xc buffer).
__global__ __launch_bounds__(256)
void k_scan_p2(const float* xc0, const float* __restrict__ dg0,
               const float* __restrict__ B0, const float* __restrict__ C0,
               const float* __restrict__ Al0, const float* __restrict__ Dv0,
               float* y0,
               const float* xc1, const float* __restrict__ dg1,
               const float* __restrict__ B1, const float* __restrict__ C1,
               const float* __restrict__ Al1, const float* __restrict__ Dv1,
               float* y1,
               const float* __restrict__ hin)
{
    __shared__ float sB[CHL*SN];
    __shared__ float sC[CHL*SN];
    int blk = blockIdx.x;
    int c = blk & (NCH-1); int dir = (blk>>7) & 1; int b = blk>>8;
    const float* xc   = dir ? xc1 : xc0;
    const float* dg   = dir ? dg1 : dg0;
    const float* Bg   = dir ? B1  : B0;
    const float* Cg   = dir ? C1  : C0;
    const float* Alog = dir ? Al1 : Al0;
    const float* Dv   = dir ? Dv1 : Dv0;
    float* y          = dir ? y1  : y0;
    int d = threadIdx.x;
    #pragma unroll
    for (int k = 0; k < 2; ++k){
        int li = threadIdx.x + k*256;
        int i = li >> 4, n = li & 15;
        int tau = c*CHL + i;
        int t = dir ? (SS-1-tau) : tau;
        sB[li] = Bg[((size_t)b*SS + t)*SN + n];
        sC[li] = Cg[((size_t)b*SS + t)*SN + n];
    }
    float A[SN];
    #pragma unroll
    for (int k = 0; k < 4; ++k){
        float4 al = *(const float4*)(Alog + d*SN + k*4);
        A[k*4+0] = -__expf(al.x); A[k*4+1] = -__expf(al.y);
        A[k*4+2] = -__expf(al.z); A[k*4+3] = -__expf(al.w);
    }
    float h[SN];
    {
        size_t base = (((size_t)(b*2+dir)*NCH + c)*SD + d)*SN;
        #pragma unroll
        for (int k = 0; k < 4; ++k){
            float4 hv = *(const float4*)(hin + base + k*4);
            h[k*4+0]=hv.x; h[k*4+1]=hv.y; h[k*4+2]=hv.z; h[k*4+3]=hv.w;
        }
    }
    float Dd = Dv[d];
    __syncthreads();
    int t0 = dir ? (SS-1 - c*CHL) : (c*CHL);
    const float* pd = dg + ((size_t)b*SS + t0)*SD + d;
    const float* px = xc + ((size_t)b*SS + t0)*SD + d;
    float* py       = y  + ((size_t)b*SS + t0)*SD + d;
    int stride = dir ? -SD : SD;
    float dl = *pd, xv = *px;
    for (int i = 0; i < CHL; ++i){
        float dlN = 0.f, xvN = 0.f;
        if (i+1 < CHL){ pd += stride; px += stride; dlN = *pd; xvN = *px; }
        float dlx = dl * xv;
        float yv = Dd * xv;
        const float4* b4 = (const float4*)&sB[i*SN];
        const float4* c4 = (const float4*)&sC[i*SN];
        #pragma unroll
        for (int k = 0; k < 4; ++k){
            float4 bb = b4[k];
            float4 cc = c4[k];
            h[k*4+0] = fmaf(__expf(dl*A[k*4+0]), h[k*4+0], bb.x*dlx);
            yv = fmaf(h[k*4+0], cc.x, yv);
            h[k*4+1] = fmaf(__expf(dl*A[k*4+1]), h[k*4+1], bb.y*dlx);
            yv = fmaf(h[k*4+1], cc.y, yv);
            h[k*4+2] = fmaf(__expf(dl*A[k*4+2]), h[k*4+2], bb.z*dlx);
            yv = fmaf(h[k*4+2], cc.z, yv);
            h[k*4+3] = fmaf(__expf(dl*A[k*4+3]), h[k*4+3], bb.w*dlx);
            yv = fmaf(h[k*4+3], cc.w, yv);
        }
        *py = yv; py += stride;
        dl = dlN; xv = xvN;
    }
}

// out = (silu(yf) + silu(yb)) * silu(z1) + x
__global__ __launch_bounds__(256)
void k_combine(const float* __restrict__ yf, const float* __restrict__ yb,
               const float* __restrict__ z1, const float* __restrict__ x,
               float* __restrict__ out, int nvec)
{
    int i = blockIdx.x*256 + threadIdx.x;
    if (i < nvec){
        float4 a = ((const float4*)yf)[i];
        float4 bq = ((const float4*)yb)[i];
        float4 zq = ((const float4*)z1)[i];
        float4 xq = ((const float4*)x)[i];
        float4 o;
        o.x = (silu_f(a.x) + silu_f(bq.x)) * silu_f(zq.x) + xq.x;
        o.y = (silu_f(a.y) + silu_f(bq.y)) * silu_f(zq.y) + xq.y;
        o.z = (silu_f(a.z) + silu_f(bq.z)) * silu_f(zq.z) + xq.z;
        o.w = (silu_f(a.w) + silu_f(bq.w)) * silu_f(zq.w) + xq.w;
        ((float4*)out)[i] = o;
    }
}

extern "C" void kernel_launch(void* const* d_in, const int* in_sizes, int n_in,
                              void* d_out, int out_size, void* d_ws, size_t ws_size,
                              hipStream_t stream) {
    const float* x     = (const float*)d_in[0];
    const float* ln_g  = (const float*)d_in[1];
    const float* ln_b  = (const float*)d_in[2];
    const float* Wp    = (const float*)d_in[3];
    const float* bp    = (const float*)d_in[4];
    const float* Wcf   = (const float*)d_in[5];
    const float* bcf   = (const float*)d_in[6];
    const float* Wcb   = (const float*)d_in[7];
    const float* bcb   = (const float*)d_in[8];
    const float* Wdbc_f= (const float*)d_in[9];
    const float* Wdt_f = (const float*)d_in[10];
    const float* bdt_f = (const float*)d_in[11];
    const float* Alog_f= (const float*)d_in[12];
    const float* D_f   = (const float*)d_in[13];
    const float* Wdbc_b= (const float*)d_in[14];
    const float* Wdt_b = (const float*)d_in[15];
    const float* bdt_b = (const float*)d_in[16];
    const float* Alog_b= (const float*)d_in[17];
    const float* D_b   = (const float*)d_in[18];
    float* out = (float*)d_out;

    float* ws = (float*)d_ws;
    const size_t NTOK  = (size_t)SB*SS;           // 16384
    const size_t SZ_BD = NTOK*SD;                 // 4,194,304
    const size_t SZ_BN = NTOK*SN;                 // 262,144
    size_t off = 0;
    float* z1    = ws + off; off += SZ_BD;
    float* xcg0  = ws + off; off += SZ_BD;
    float* xcg1  = ws + off; off += SZ_BD;
    float* dg0   = ws + off; off += SZ_BD;
    float* dg1   = ws + off; off += SZ_BD;
    float* Bg0   = ws + off; off += SZ_BN;
    float* Bg1   = ws + off; off += SZ_BN;
    float* Cg0   = ws + off; off += SZ_BN;
    float* Cg1   = ws + off; off += SZ_BN;
    float* WcfT  = ws + off; off += (size_t)SD*SD;
    float* WcbT  = ws + off; off += (size_t)SD*SD;
    float* hend  = ws + off; off += (size_t)8*NCH*SD*SN;   // 4,194,304
    float* sdl   = ws + off; off += (size_t)8*NCH*SD;      // 262,144
    // y aliases xc (read-then-write per element within the owning thread)
    float* y0 = xcg0;
    float* y1 = xcg1;

    k_transpose<<<512, 256, 0, stream>>>(Wcf, Wcb, WcfT, WcbT);
    k_ln_proj<<<NRB, 256, 0, stream>>>(x, ln_g, ln_b, Wp, bp, z1);
    k_pointwise<<<NRB, 256, 0, stream>>>(z1,
        WcfT, bcf, Wdbc_f, Wdt_f, bdt_f,
        WcbT, bcb, Wdbc_b, Wdt_b, bdt_b,
        xcg0, dg0, Bg0, Cg0,
        xcg1, dg1, Bg1, Cg1);
    k_scan_p1<<<1024, 256, 0, stream>>>(xcg0, dg0, Bg0, Alog_f,
                                        xcg1, dg1, Bg1, Alog_b, hend, sdl);
    k_chain<<<128, 256, 0, stream>>>(Alog_f, Alog_b, hend, sdl);
    k_scan_p2<<<1024, 256, 0, stream>>>(
        xcg0, dg0, Bg0, Cg0, Alog_f, D_f, y0,
        xcg1, dg1, Bg1, Cg1, Alog_b, D_b, y1,
        hend);
    k_combine<<<4096, 256, 0, stream>>>(y0, y1, z1, x, out, (int)(SZ_BD/4));
}

// Round 3
// 238.895 us; speedup vs baseline: 1.9608x; 1.0050x over previous
//
#include <hip/hip_runtime.h>
#include <math.h>

#define SB 4
#define SS 4096
#define SD 256
#define SN 16
#define SR 16
#define ROWS 16
#define NRB 1024        // 16384 rows / 16
#define NCH 128         // chunks per (b,dir)
#define CHL 32          // chunk length; NCH*CHL = SS

__device__ __forceinline__ float softplus_f(float x){
    return fmaxf(x, 0.f) + __logf(1.f + __expf(-fabsf(x)));
}
__device__ __forceinline__ float silu_f(float x){
    return x * __builtin_amdgcn_rcpf(1.f + __expf(-x));
}

// Transpose Wcf/Wcb (used as x @ Wc.T) so the conv GEMM reads coalesced.
__global__ __launch_bounds__(256)
void k_transpose(const float* __restrict__ W0, const float* __restrict__ W1,
                 float* __restrict__ T0, float* __restrict__ T1){
    int blk = blockIdx.x;            // 0..511
    int d = blk & 255; int which = blk >> 8;
    int e = threadIdx.x;
    const float* W = which ? W1 : W0;
    float* T = which ? T1 : T0;
    T[d*SD + e] = W[e*SD + d];
}

// LayerNorm + z1 = xn @ Wp + bp.  16 rows/block, 4x4 register tile GEMM.
__global__ __launch_bounds__(256, 4)
void k_ln_proj(const float* __restrict__ x, const float* __restrict__ g,
               const float* __restrict__ bln, const float* __restrict__ Wp,
               const float* __restrict__ bp, float* __restrict__ z1){
    __shared__ float xnT[ROWS][SD];
    int row0 = blockIdx.x * ROWS;
    int tid = threadIdx.x; int w = tid >> 6; int lane = tid & 63;
    #pragma unroll
    for (int rep = 0; rep < 4; ++rep){
        int j = rep*4 + w;
        const float* xr = x + (size_t)(row0 + j)*SD;
        float4 v = *(const float4*)(xr + lane*4);
        float s = v.x + v.y + v.z + v.w;
        #pragma unroll
        for (int off = 32; off; off >>= 1) s += __shfl_xor(s, off, 64);
        float mu = s * (1.f/256.f);
        float d0 = v.x-mu, d1 = v.y-mu, d2 = v.z-mu, d3 = v.w-mu;
        float q = d0*d0 + d1*d1 + d2*d2 + d3*d3;
        #pragma unroll
        for (int off = 32; off; off >>= 1) q += __shfl_xor(q, off, 64);
        float rstd = rsqrtf(q*(1.f/256.f) + 1e-5f);
        float4 gg = *(const float4*)(g + lane*4);
        float4 bb = *(const float4*)(bln + lane*4);
        float4 o;
        o.x = d0*rstd*gg.x + bb.x;
        o.y = d1*rstd*gg.y + bb.y;
        o.z = d2*rstd*gg.z + bb.z;
        o.w = d3*rstd*gg.w + bb.w;
        *(float4*)&xnT[j][lane*4] = o;   // contiguous b128, conflict-free
    }
    __syncthreads();
    int tx = tid & 63; int ty = tid >> 6;       // ty = wave id -> uniform LDS reads
    float4 acc[4];
    float4 bp4 = *(const float4*)(bp + tx*4);
    #pragma unroll
    for (int q = 0; q < 4; ++q) acc[q] = bp4;
    for (int d4 = 0; d4 < SD; d4 += 4){
        float4 wv[4];
        #pragma unroll
        for (int k = 0; k < 4; ++k)
            wv[k] = *(const float4*)(Wp + (size_t)(d4+k)*SD + tx*4);
        float4 a[4];
        #pragma unroll
        for (int q = 0; q < 4; ++q) a[q] = *(const float4*)&xnT[ty*4+q][d4];
        #pragma unroll
        for (int k = 0; k < 4; ++k){
            #pragma unroll
            for (int q = 0; q < 4; ++q){
                float av = ((const float*)&a[q])[k];
                acc[q].x = fmaf(av, wv[k].x, acc[q].x);
                acc[q].y = fmaf(av, wv[k].y, acc[q].y);
                acc[q].z = fmaf(av, wv[k].z, acc[q].z);
                acc[q].w = fmaf(av, wv[k].w, acc[q].w);
            }
        }
    }
    #pragma unroll
    for (int q = 0; q < 4; ++q)
        *(float4*)(z1 + (size_t)(row0 + ty*4 + q)*SD + tx*4) = acc[q];
}

// Per-direction pointwise, DIRS FUSED: xc = softplus(z1 @ WcT + bc);
// dbc = xc @ Wdbc; delta = softplus(dt_r @ Wdt + bdt); emits xc, delta, B, C.
__global__ __launch_bounds__(256, 4)
void k_pointwise(const float* __restrict__ z1,
                 const float* __restrict__ WcT0, const float* __restrict__ bc0,
                 const float* __restrict__ Wdbc0, const float* __restrict__ Wdt0, const float* __restrict__ bdt0,
                 const float* __restrict__ WcT1, const float* __restrict__ bc1,
                 const float* __restrict__ Wdbc1, const float* __restrict__ Wdt1, const float* __restrict__ bdt1,
                 float* __restrict__ xcg0, float* __restrict__ dg0, float* __restrict__ Bg0, float* __restrict__ Cg0,
                 float* __restrict__ xcg1, float* __restrict__ dg1, float* __restrict__ Bg1, float* __restrict__ Cg1)
{
    __shared__ float z1T[ROWS][SD];      // becomes xcT1 after main GEMM
    __shared__ float xcT0[ROWS][SD];
    __shared__ float dbcT0[ROWS][49];
    __shared__ float dbcT1[ROWS][49];
    float (*xcT1)[SD] = z1T;
    int row0 = blockIdx.x * ROWS;
    int tid = threadIdx.x;
    int tx = tid & 63; int ty = tid >> 6;
    // stage z1 tile: 16 consecutive rows = 16KB contiguous
    {
        const float4* zsrc = (const float4*)(z1 + (size_t)row0*SD);
        float4* zdst = (float4*)&z1T[0][0];
        #pragma unroll
        for (int k = 0; k < 4; ++k) zdst[tid + k*256] = zsrc[tid + k*256];
    }
    __syncthreads();

    // main GEMM, both dirs in one pass over d
    float4 acc0[4], acc1[4];
    {
        float4 b0 = *(const float4*)(bc0 + tx*4);
        float4 b1 = *(const float4*)(bc1 + tx*4);
        #pragma unroll
        for (int q = 0; q < 4; ++q){ acc0[q] = b0; acc1[q] = b1; }
    }
    for (int d4 = 0; d4 < SD; d4 += 4){
        float4 w0[4], w1[4];
        #pragma unroll
        for (int k = 0; k < 4; ++k){
            w0[k] = *(const float4*)(WcT0 + (size_t)(d4+k)*SD + tx*4);
            w1[k] = *(const float4*)(WcT1 + (size_t)(d4+k)*SD + tx*4);
        }
        float4 a[4];
        #pragma unroll
        for (int q = 0; q < 4; ++q) a[q] = *(const float4*)&z1T[ty*4+q][d4];
        #pragma unroll
        for (int k = 0; k < 4; ++k){
            #pragma unroll
            for (int q = 0; q < 4; ++q){
                float av = ((const float*)&a[q])[k];
                acc0[q].x = fmaf(av, w0[k].x, acc0[q].x);
                acc0[q].y = fmaf(av, w0[k].y, acc0[q].y);
                acc0[q].z = fmaf(av, w0[k].z, acc0[q].z);
                acc0[q].w = fmaf(av, w0[k].w, acc0[q].w);
                acc1[q].x = fmaf(av, w1[k].x, acc1[q].x);
                acc1[q].y = fmaf(av, w1[k].y, acc1[q].y);
                acc1[q].z = fmaf(av, w1[k].z, acc1[q].z);
                acc1[q].w = fmaf(av, w1[k].w, acc1[q].w);
            }
        }
    }
    __syncthreads();   // all z1T reads done before overwrite as xcT1
    #pragma unroll
    for (int q = 0; q < 4; ++q){
        float4 o0, o1;
        o0.x = softplus_f(acc0[q].x); o0.y = softplus_f(acc0[q].y);
        o0.z = softplus_f(acc0[q].z); o0.w = softplus_f(acc0[q].w);
        o1.x = softplus_f(acc1[q].x); o1.y = softplus_f(acc1[q].y);
        o1.z = softplus_f(acc1[q].z); o1.w = softplus_f(acc1[q].w);
        *(float4*)&xcT0[ty*4+q][tx*4] = o0;
        *(float4*)(xcg0 + (size_t)(row0 + ty*4 + q)*SD + tx*4) = o0;
        *(float4*)&xcT1[ty*4+q][tx*4] = o1;
        *(float4*)(xcg1 + (size_t)(row0 + ty*4 + q)*SD + tx*4) = o1;
    }
    __syncthreads();
    // dbc = xc @ Wdbc  (48 cols), both dirs
    if (tx < 48){
        float a20[4] = {0.f,0.f,0.f,0.f};
        float a21[4] = {0.f,0.f,0.f,0.f};
        for (int d4 = 0; d4 < SD; d4 += 4){
            float w0[4], w1[4];
            #pragma unroll
            for (int k = 0; k < 4; ++k){
                w0[k] = Wdbc0[(size_t)(d4+k)*48 + tx];
                w1[k] = Wdbc1[(size_t)(d4+k)*48 + tx];
            }
            #pragma unroll
            for (int q = 0; q < 4; ++q){
                float4 x0 = *(const float4*)&xcT0[ty*4+q][d4];
                float4 x1 = *(const float4*)&xcT1[ty*4+q][d4];
                a20[q] = fmaf(x0.x, w0[0], a20[q]);
                a20[q] = fmaf(x0.y, w0[1], a20[q]);
                a20[q] = fmaf(x0.z, w0[2], a20[q]);
                a20[q] = fmaf(x0.w, w0[3], a20[q]);
                a21[q] = fmaf(x1.x, w1[0], a21[q]);
                a21[q] = fmaf(x1.y, w1[1], a21[q]);
                a21[q] = fmaf(x1.z, w1[2], a21[q]);
                a21[q] = fmaf(x1.w, w1[3], a21[q]);
            }
        }
        #pragma unroll
        for (int q = 0; q < 4; ++q){
            dbcT0[ty*4+q][tx] = a20[q];
            dbcT1[ty*4+q][tx] = a21[q];
        }
    }
    __syncthreads();
    // B, C extraction (coalesced: global idx == row0*16 + tid)
    {
        int j = tid >> 4; int n = tid & 15;
        Bg0[(size_t)(row0+j)*SN + n] = dbcT0[j][16+n];
        Cg0[(size_t)(row0+j)*SN + n] = dbcT0[j][32+n];
        Bg1[(size_t)(row0+j)*SN + n] = dbcT1[j][16+n];
        Cg1[(size_t)(row0+j)*SN + n] = dbcT1[j][32+n];
    }
    // delta = softplus(dt_r @ Wdt + bdt), both dirs
    float4 a30[4], a31[4];
    {
        float4 b0 = *(const float4*)(bdt0 + tx*4);
        float4 b1 = *(const float4*)(bdt1 + tx*4);
        #pragma unroll
        for (int q = 0; q < 4; ++q){ a30[q] = b0; a31[q] = b1; }
    }
    #pragma unroll
    for (int r = 0; r < SR; ++r){
        float4 w0 = *(const float4*)(Wdt0 + (size_t)r*SD + tx*4);
        float4 w1 = *(const float4*)(Wdt1 + (size_t)r*SD + tx*4);
        #pragma unroll
        for (int q = 0; q < 4; ++q){
            float a0 = dbcT0[ty*4+q][r];
            float a1 = dbcT1[ty*4+q][r];
            a30[q].x = fmaf(a0, w0.x, a30[q].x);
            a30[q].y = fmaf(a0, w0.y, a30[q].y);
            a30[q].z = fmaf(a0, w0.z, a30[q].z);
            a30[q].w = fmaf(a0, w0.w, a30[q].w);
            a31[q].x = fmaf(a1, w1.x, a31[q].x);
            a31[q].y = fmaf(a1, w1.y, a31[q].y);
            a31[q].z = fmaf(a1, w1.z, a31[q].z);
            a31[q].w = fmaf(a1, w1.w, a31[q].w);
        }
    }
    #pragma unroll
    for (int q = 0; q < 4; ++q){
        float4 o0, o1;
        o0.x = softplus_f(a30[q].x); o0.y = softplus_f(a30[q].y);
        o0.z = softplus_f(a30[q].z); o0.w = softplus_f(a30[q].w);
        o1.x = softplus_f(a31[q].x); o1.y = softplus_f(a31[q].y);
        o1.z = softplus_f(a31[q].z); o1.w = softplus_f(a31[q].w);
        *(float4*)(dg0 + (size_t)(row0 + ty*4 + q)*SD + tx*4) = o0;
        *(float4*)(dg1 + (size_t)(row0 + ty*4 + q)*SD + tx*4) = o1;
    }
}

// Scan pass 1: per-chunk h_end + sum(delta). Thread owns one d, 16 states in regs.
__global__ __launch_bounds__(256)
void k_scan_p1(const float* __restrict__ xc0, const float* __restrict__ dg0,
               const float* __restrict__ B0,  const float* __restrict__ Al0,
               const float* __restrict__ xc1, const float* __restrict__ dg1,
               const float* __restrict__ B1,  const float* __restrict__ Al1,
               float* __restrict__ hend, float* __restrict__ sdl)
{
    __shared__ float sB[CHL*SN];
    int blk = blockIdx.x;                 // 1024 = b(4) * dir(2) * c(128)
    int c = blk & (NCH-1); int dir = (blk>>7) & 1; int b = blk>>8;
    const float* xc   = dir ? xc1 : xc0;
    const float* dg   = dir ? dg1 : dg0;
    const float* Bg   = dir ? B1  : B0;
    const float* Alog = dir ? Al1 : Al0;
    int d = threadIdx.x;
    #pragma unroll
    for (int k = 0; k < 2; ++k){
        int li = threadIdx.x + k*256;
        int i = li >> 4, n = li & 15;
        int tau = c*CHL + i;
        int t = dir ? (SS-1-tau) : tau;
        sB[li] = Bg[((size_t)b*SS + t)*SN + n];
    }
    float A[SN];
    #pragma unroll
    for (int k = 0; k < 4; ++k){
        float4 al = *(const float4*)(Alog + d*SN + k*4);
        A[k*4+0] = -__expf(al.x); A[k*4+1] = -__expf(al.y);
        A[k*4+2] = -__expf(al.z); A[k*4+3] = -__expf(al.w);
    }
    __syncthreads();
    int t0 = dir ? (SS-1 - c*CHL) : (c*CHL);
    const float* pd = dg + ((size_t)b*SS + t0)*SD + d;
    const float* px = xc + ((size_t)b*SS + t0)*SD + d;
    int stride = dir ? -SD : SD;
    float h[SN];
    #pragma unroll
    for (int n = 0; n < SN; ++n) h[n] = 0.f;
    float sumdl = 0.f;
    float dl = *pd, xv = *px;
    for (int i = 0; i < CHL; ++i){
        float dlN = 0.f, xvN = 0.f;
        if (i+1 < CHL){ pd += stride; px += stride; dlN = *pd; xvN = *px; }
        sumdl += dl;
        float dlx = dl * xv;
        const float4* b4 = (const float4*)&sB[i*SN];
        #pragma unroll
        for (int k = 0; k < 4; ++k){
            float4 bb = b4[k];
            h[k*4+0] = fmaf(__expf(dl*A[k*4+0]), h[k*4+0], bb.x*dlx);
            h[k*4+1] = fmaf(__expf(dl*A[k*4+1]), h[k*4+1], bb.y*dlx);
            h[k*4+2] = fmaf(__expf(dl*A[k*4+2]), h[k*4+2], bb.z*dlx);
            h[k*4+3] = fmaf(__expf(dl*A[k*4+3]), h[k*4+3], bb.w*dlx);
        }
        dl = dlN; xv = xvN;
    }
    size_t base = (((size_t)(b*2+dir)*NCH + c)*SD + d)*SN;
    #pragma unroll
    for (int k = 0; k < 4; ++k)
        *(float4*)(hend + base + k*4) = make_float4(h[k*4+0],h[k*4+1],h[k*4+2],h[k*4+3]);
    sdl[((size_t)(b*2+dir)*NCH + c)*SD + d] = sumdl;
}

// Chain chunks serially per (b,dir,d,n); in-place turns hend into h_in.
// Prefetch depth 4 to hide load latency (no other waves to hide behind).
__global__ __launch_bounds__(256)
void k_chain(const float* __restrict__ Al0, const float* __restrict__ Al1,
             float* hend, const float* __restrict__ sdl)
{
    int gidx = blockIdx.x*256 + threadIdx.x;       // 32768
    int n = gidx & 15; int d = (gidx >> 4) & 255; int dirb = gidx >> 12;
    const float* Alog = (dirb & 1) ? Al1 : Al0;
    float A = -__expf(Alog[d*SN + n]);
    float H = 0.f;
    const size_t cs = (size_t)SD*SN;               // 4096
    size_t idx  = (size_t)dirb*NCH*cs + (size_t)d*SN + n;
    size_t sidx = (size_t)dirb*NCH*SD + d;
    float he[4], sd[4];
    #pragma unroll
    for (int k = 0; k < 4; ++k){
        he[k] = hend[idx + (size_t)k*cs];
        sd[k] = sdl[sidx + (size_t)k*SD];
    }
    for (int cg = 0; cg < NCH; cg += 4){
        float heN[4] = {0.f,0.f,0.f,0.f};
        float sdN[4] = {0.f,0.f,0.f,0.f};
        if (cg + 4 < NCH){
            #pragma unroll
            for (int k = 0; k < 4; ++k){
                heN[k] = hend[idx + (size_t)(k+4)*cs];
                sdN[k] = sdl[sidx + (size_t)(k+4)*SD];
            }
        }
        #pragma unroll
        for (int k = 0; k < 4; ++k){
            hend[idx + (size_t)k*cs] = H;           // now holds h_in
            H = fmaf(__expf(A*sd[k]), H, he[k]);
        }
        #pragma unroll
        for (int k = 0; k < 4; ++k){ he[k] = heN[k]; sd[k] = sdN[k]; }
        idx += 4*cs; sidx += 4*SD;
    }
}

// Scan pass 2: recompute with h_in, emit y (aliases the xc buffer).
__global__ __launch_bounds__(256)
void k_scan_p2(const float* xc0, const float* __restrict__ dg0,
               const float* __restrict__ B0, const float* __restrict__ C0,
               const float* __restrict__ Al0, const float* __restrict__ Dv0,
               float* y0,
               const float* xc1, const float* __restrict__ dg1,
               const float* __restrict__ B1, const float* __restrict__ C1,
               const float* __restrict__ Al1, const float* __restrict__ Dv1,
               float* y1,
               const float* __restrict__ hin)
{
    __shared__ float sB[CHL*SN];
    __shared__ float sC[CHL*SN];
    int blk = blockIdx.x;
    int c = blk & (NCH-1); int dir = (blk>>7) & 1; int b = blk>>8;
    const float* xc   = dir ? xc1 : xc0;
    const float* dg   = dir ? dg1 : dg0;
    const float* Bg   = dir ? B1  : B0;
    const float* Cg   = dir ? C1  : C0;
    const float* Alog = dir ? Al1 : Al0;
    const float* Dv   = dir ? Dv1 : Dv0;
    float* y          = dir ? y1  : y0;
    int d = threadIdx.x;
    #pragma unroll
    for (int k = 0; k < 2; ++k){
        int li = threadIdx.x + k*256;
        int i = li >> 4, n = li & 15;
        int tau = c*CHL + i;
        int t = dir ? (SS-1-tau) : tau;
        sB[li] = Bg[((size_t)b*SS + t)*SN + n];
        sC[li] = Cg[((size_t)b*SS + t)*SN + n];
    }
    float A[SN];
    #pragma unroll
    for (int k = 0; k < 4; ++k){
        float4 al = *(const float4*)(Alog + d*SN + k*4);
        A[k*4+0] = -__expf(al.x); A[k*4+1] = -__expf(al.y);
        A[k*4+2] = -__expf(al.z); A[k*4+3] = -__expf(al.w);
    }
    float h[SN];
    {
        size_t base = (((size_t)(b*2+dir)*NCH + c)*SD + d)*SN;
        #pragma unroll
        for (int k = 0; k < 4; ++k){
            float4 hv = *(const float4*)(hin + base + k*4);
            h[k*4+0]=hv.x; h[k*4+1]=hv.y; h[k*4+2]=hv.z; h[k*4+3]=hv.w;
        }
    }
    float Dd = Dv[d];
    __syncthreads();
    int t0 = dir ? (SS-1 - c*CHL) : (c*CHL);
    const float* pd = dg + ((size_t)b*SS + t0)*SD + d;
    const float* px = xc + ((size_t)b*SS + t0)*SD + d;
    float* py       = y  + ((size_t)b*SS + t0)*SD + d;
    int stride = dir ? -SD : SD;
    float dl = *pd, xv = *px;
    for (int i = 0; i < CHL; ++i){
        float dlN = 0.f, xvN = 0.f;
        if (i+1 < CHL){ pd += stride; px += stride; dlN = *pd; xvN = *px; }
        float dlx = dl * xv;
        float yv = Dd * xv;
        const float4* b4 = (const float4*)&sB[i*SN];
        const float4* c4 = (const float4*)&sC[i*SN];
        #pragma unroll
        for (int k = 0; k < 4; ++k){
            float4 bb = b4[k];
            float4 cc = c4[k];
            h[k*4+0] = fmaf(__expf(dl*A[k*4+0]), h[k*4+0], bb.x*dlx);
            yv = fmaf(h[k*4+0], cc.x, yv);
            h[k*4+1] = fmaf(__expf(dl*A[k*4+1]), h[k*4+1], bb.y*dlx);
            yv = fmaf(h[k*4+1], cc.y, yv);
            h[k*4+2] = fmaf(__expf(dl*A[k*4+2]), h[k*4+2], bb.z*dlx);
            yv = fmaf(h[k*4+2], cc.z, yv);
            h[k*4+3] = fmaf(__expf(dl*A[k*4+3]), h[k*4+3], bb.w*dlx);
            yv = fmaf(h[k*4+3], cc.w, yv);
        }
        *py = yv; py += stride;
        dl = dlN; xv = xvN;
    }
}

// out = (silu(yf) + silu(yb)) * silu(z1) + x
__global__ __launch_bounds__(256)
void k_combine(const float* __restrict__ yf, const float* __restrict__ yb,
               const float* __restrict__ z1, const float* __restrict__ x,
               float* __restrict__ out, int nvec)
{
    int i = blockIdx.x*256 + threadIdx.x;
    if (i < nvec){
        float4 a = ((const float4*)yf)[i];
        float4 bq = ((const float4*)yb)[i];
        float4 zq = ((const float4*)z1)[i];
        float4 xq = ((const float4*)x)[i];
        float4 o;
        o.x = (silu_f(a.x) + silu_f(bq.x)) * silu_f(zq.x) + xq.x;
        o.y = (silu_f(a.y) + silu_f(bq.y)) * silu_f(zq.y) + xq.y;
        o.z = (silu_f(a.z) + silu_f(bq.z)) * silu_f(zq.z) + xq.z;
        o.w = (silu_f(a.w) + silu_f(bq.w)) * silu_f(zq.w) + xq.w;
        ((float4*)out)[i] = o;
    }
}

extern "C" void kernel_launch(void* const* d_in, const int* in_sizes, int n_in,
                              void* d_out, int out_size, void* d_ws, size_t ws_size,
                              hipStream_t stream) {
    const float* x     = (const float*)d_in[0];
    const float* ln_g  = (const float*)d_in[1];
    const float* ln_b  = (const float*)d_in[2];
    const float* Wp    = (const float*)d_in[3];
    const float* bp    = (const float*)d_in[4];
    const float* Wcf   = (const float*)d_in[5];
    const float* bcf   = (const float*)d_in[6];
    const float* Wcb   = (const float*)d_in[7];
    const float* bcb   = (const float*)d_in[8];
    const float* Wdbc_f= (const float*)d_in[9];
    const float* Wdt_f = (const float*)d_in[10];
    const float* bdt_f = (const float*)d_in[11];
    const float* Alog_f= (const float*)d_in[12];
    const float* D_f   = (const float*)d_in[13];
    const float* Wdbc_b= (const float*)d_in[14];
    const float* Wdt_b = (const float*)d_in[15];
    const float* bdt_b = (const float*)d_in[16];
    const float* Alog_b= (const float*)d_in[17];
    const float* D_b   = (const float*)d_in[18];
    float* out = (float*)d_out;

    float* ws = (float*)d_ws;
    const size_t NTOK  = (size_t)SB*SS;           // 16384
    const size_t SZ_BD = NTOK*SD;                 // 4,194,304
    const size_t SZ_BN = NTOK*SN;                 // 262,144
    size_t off = 0;
    float* z1    = ws + off; off += SZ_BD;
    float* xcg0  = ws + off; off += SZ_BD;
    float* xcg1  = ws + off; off += SZ_BD;
    float* dg0   = ws + off; off += SZ_BD;
    float* dg1   = ws + off; off += SZ_BD;
    float* Bg0   = ws + off; off += SZ_BN;
    float* Bg1   = ws + off; off += SZ_BN;
    float* Cg0   = ws + off; off += SZ_BN;
    float* Cg1   = ws + off; off += SZ_BN;
    float* WcfT  = ws + off; off += (size_t)SD*SD;
    float* WcbT  = ws + off; off += (size_t)SD*SD;
    float* hend  = ws + off; off += (size_t)8*NCH*SD*SN;   // 4,194,304
    float* sdl   = ws + off; off += (size_t)8*NCH*SD;      // 262,144
    // y aliases xc (read-then-write per element within the owning thread)
    float* y0 = xcg0;
    float* y1 = xcg1;

    k_transpose<<<512, 256, 0, stream>>>(Wcf, Wcb, WcfT, WcbT);
    k_ln_proj<<<NRB, 256, 0, stream>>>(x, ln_g, ln_b, Wp, bp, z1);
    k_pointwise<<<NRB, 256, 0, stream>>>(z1,
        WcfT, bcf, Wdbc_f, Wdt_f, bdt_f,
        WcbT, bcb, Wdbc_b, Wdt_b, bdt_b,
        xcg0, dg0, Bg0, Cg0,
        xcg1, dg1, Bg1, Cg1);
    k_scan_p1<<<1024, 256, 0, stream>>>(xcg0, dg0, Bg0, Alog_f,
                                        xcg1, dg1, Bg1, Alog_b, hend, sdl);
    k_chain<<<128, 256, 0, stream>>>(Alog_f, Alog_b, hend, sdl);
    k_scan_p2<<<1024, 256, 0, stream>>>(
        xcg0, dg0, Bg0, Cg0, Alog_f, D_f, y0,
        xcg1, dg1, Bg1, Cg1, Alog_b, D_b, y1,
        hend);
    k_combine<<<4096, 256, 0, stream>>>(y0, y1, z1, x, out, (int)(SZ_BD/4));
}

// Round 5
// 211.078 us; speedup vs baseline: 2.2192x; 1.1318x over previous
//
#include <hip/hip_runtime.h>
#include <math.h>

#define SB 4
#define SS 4096
#define SD 256
#define SN 16
#define ROWS 16
#define NRB 1024        // 16384 rows / 16
#define NCH 128         // chunks per (b,dir)
#define CHL 32          // chunk length; NCH*CHL = SS

// MFMA GEMM tile
#define BM 128
#define BN 64
#define BK 64
#define LDT 72          // BK + 8 bf16 pad (keeps 16B alignment, kills bank conflicts)

typedef __attribute__((ext_vector_type(8))) short bf16x8;
typedef __attribute__((ext_vector_type(4))) float f32x4;

__device__ __forceinline__ unsigned short f2bf(float f){
    unsigned int u = __float_as_uint(f);
    u += 0x7FFFu + ((u >> 16) & 1u);        // round-to-nearest-even
    return (unsigned short)(u >> 16);
}
__device__ __forceinline__ float bf2f(unsigned short u){
    return __uint_as_float(((unsigned int)u) << 16);
}
__device__ __forceinline__ float softplus_f(float x){
    return fmaxf(x, 0.f) + __logf(1.f + __expf(-fabsf(x)));
}
__device__ __forceinline__ float silu_f(float x){
    return x * __builtin_amdgcn_rcpf(1.f + __expf(-x));
}

// Weight prep: bf16 conversions + Wdelta = Wdbc[:,:16] @ Wdt fold.
// region0: WpT[n*256+k] = Wp[k*256+n]            (65536)
// region1: Wc[e*256+d]  = (e<256?Wcf:Wcb)[e][d]  (131072)
// region2: G3W[dir][n*256+d], n<256: Wdelta^T; 256..271: B-cols; 272..287: C-cols; 288..319: 0  (163840)
__global__ __launch_bounds__(256)
void k_prep(const float* __restrict__ Wp,
            const float* __restrict__ Wcf, const float* __restrict__ Wcb,
            const float* __restrict__ Wdbc0, const float* __restrict__ Wdt0,
            const float* __restrict__ Wdbc1, const float* __restrict__ Wdt1,
            unsigned short* __restrict__ WpT, unsigned short* __restrict__ Wc,
            unsigned short* __restrict__ G3W)
{
    int idx = blockIdx.x*256 + threadIdx.x;
    if (idx < 65536){
        int n = idx >> 8, k = idx & 255;
        WpT[idx] = f2bf(Wp[k*256 + n]);
    } else if (idx < 65536 + 131072){
        int j = idx - 65536;
        Wc[j] = f2bf(j < 65536 ? Wcf[j] : Wcb[j - 65536]);
    } else {
        int j = idx - 196608;               // 0 .. 163839
        int dir = j / 81920; int r = j - dir*81920;
        int n = r >> 8, d = r & 255;
        const float* Wdbc = dir ? Wdbc1 : Wdbc0;
        const float* Wdt  = dir ? Wdt1  : Wdt0;
        float v;
        if (n < 256){
            v = 0.f;
            #pragma unroll
            for (int q = 0; q < 16; ++q)
                v = fmaf(Wdbc[d*48 + q], Wdt[q*256 + n], v);
        } else if (n < 272) v = Wdbc[d*48 + 16 + (n-256)];
        else if (n < 288)   v = Wdbc[d*48 + 32 + (n-272)];
        else                v = 0.f;
        G3W[(size_t)dir*81920 + r] = f2bf(v);
    }
}

// LayerNorm -> bf16
__global__ __launch_bounds__(256)
void k_ln(const float* __restrict__ x, const float* __restrict__ g,
          const float* __restrict__ bln, unsigned short* __restrict__ xnbf){
    int row0 = blockIdx.x * ROWS;
    int tid = threadIdx.x; int w = tid >> 6; int lane = tid & 63;
    #pragma unroll
    for (int rep = 0; rep < 4; ++rep){
        int j = rep*4 + w;
        const float* xr = x + (size_t)(row0 + j)*SD;
        float4 v = *(const float4*)(xr + lane*4);
        float s = v.x + v.y + v.z + v.w;
        #pragma unroll
        for (int off = 32; off; off >>= 1) s += __shfl_xor(s, off, 64);
        float mu = s * (1.f/256.f);
        float d0 = v.x-mu, d1 = v.y-mu, d2 = v.z-mu, d3 = v.w-mu;
        float q = d0*d0 + d1*d1 + d2*d2 + d3*d3;
        #pragma unroll
        for (int off = 32; off; off >>= 1) q += __shfl_xor(q, off, 64);
        float rstd = rsqrtf(q*(1.f/256.f) + 1e-5f);
        float4 gg = *(const float4*)(g + lane*4);
        float4 bb = *(const float4*)(bln + lane*4);
        ushort4 o;
        o.x = f2bf(d0*rstd*gg.x + bb.x);
        o.y = f2bf(d1*rstd*gg.y + bb.y);
        o.z = f2bf(d2*rstd*gg.z + bb.z);
        o.w = f2bf(d3*rstd*gg.w + bb.w);
        *(ushort4*)(xnbf + (size_t)(row0+j)*SD + lane*4) = o;
    }
}

// Tiled MFMA bf16 GEMM: C[M x N] = A[M x lda(slice K=256)] @ Bt^T, Bt is [N][256] bf16.
// 256 threads = 4 waves (2x2), wave tile 64x32, 16x16x32 frags, dbuf LDS.
// EPI 0: z1bf = v + bp                      (obf)
// EPI 1: xc = softplus(v + bc);             (o0/o1 fp32 split at col 256, obf = xc bf16 [row][512])
// EPI 2: col<256: dg = softplus(v + bdt); 256..271: Bg; 272..287: Cg  (dir = blockIdx.z)
template<int EPI>
__global__ __launch_bounds__(256)
void k_gemm(const unsigned short* __restrict__ A, int lda,
            const unsigned short* __restrict__ Bt,
            const float* __restrict__ bias0, const float* __restrict__ bias1,
            float* __restrict__ o0, float* __restrict__ o1,
            unsigned short* __restrict__ obf,
            float* __restrict__ oB0, float* __restrict__ oB1,
            float* __restrict__ oC0, float* __restrict__ oC1)
{
    __shared__ unsigned short sA[2][BM][LDT];
    __shared__ unsigned short sB[2][BN][LDT];
    int ntile = blockIdx.x, mtile = blockIdx.y;
    int dir = (EPI == 2) ? blockIdx.z : 0;
    int row0 = mtile * BM;
    int col0 = ntile * BN;
    const unsigned short* Ap  = A  + (EPI == 2 ? dir*256 : 0);
    const unsigned short* Btp = Bt + (EPI == 2 ? (size_t)dir*81920 : 0);

    int tid = threadIdx.x;
    uint4 ra[4], rb[2];
    auto gload = [&](int kt){
        int k0 = kt * BK;
        #pragma unroll
        for (int i = 0; i < 4; ++i){
            int idx = tid + i*256; int r = idx >> 3, kp = idx & 7;
            ra[i] = *(const uint4*)(Ap + (size_t)(row0 + r)*lda + k0 + kp*8);
        }
        #pragma unroll
        for (int i = 0; i < 2; ++i){
            int idx = tid + i*256; int r = idx >> 3, kp = idx & 7;
            rb[i] = *(const uint4*)(Btp + (size_t)(col0 + r)*256 + k0 + kp*8);
        }
    };
    auto swrite = [&](int buf){
        #pragma unroll
        for (int i = 0; i < 4; ++i){
            int idx = tid + i*256; int r = idx >> 3, kp = idx & 7;
            *(uint4*)&sA[buf][r][kp*8] = ra[i];
        }
        #pragma unroll
        for (int i = 0; i < 2; ++i){
            int idx = tid + i*256; int r = idx >> 3, kp = idx & 7;
            *(uint4*)&sB[buf][r][kp*8] = rb[i];
        }
    };

    gload(0); swrite(0); __syncthreads();

    int lane = tid & 63, w = tid >> 6;
    int wr = w >> 1, wc = w & 1;
    int lr = lane & 15, hi = lane >> 4;

    f32x4 acc[4][2];
    #pragma unroll
    for (int mf = 0; mf < 4; ++mf)
        #pragma unroll
        for (int nf = 0; nf < 2; ++nf)
            acc[mf][nf] = f32x4{0.f, 0.f, 0.f, 0.f};

    for (int kt = 0; kt < 4; ++kt){
        int cur = kt & 1;
        if (kt < 3) gload(kt + 1);
        #pragma unroll
        for (int kk = 0; kk < BK; kk += 32){
            bf16x8 af[4], bfr[2];
            #pragma unroll
            for (int mf = 0; mf < 4; ++mf)
                af[mf] = *(const bf16x8*)&sA[cur][wr*64 + mf*16 + lr][kk + hi*8];
            #pragma unroll
            for (int nf = 0; nf < 2; ++nf)
                bfr[nf] = *(const bf16x8*)&sB[cur][wc*32 + nf*16 + lr][kk + hi*8];
            #pragma unroll
            for (int mf = 0; mf < 4; ++mf)
                #pragma unroll
                for (int nf = 0; nf < 2; ++nf)
                    acc[mf][nf] = __builtin_amdgcn_mfma_f32_16x16x32_bf16(
                        af[mf], bfr[nf], acc[mf][nf], 0, 0, 0);
        }
        if (kt < 3){
            __syncthreads();
            swrite((kt + 1) & 1);
            __syncthreads();
        }
    }

    // epilogue
    int colB = col0 + wc*32;
    int rowB = row0 + wr*64;
    #pragma unroll
    for (int mf = 0; mf < 4; ++mf){
        #pragma unroll
        for (int nf = 0; nf < 2; ++nf){
            int col = colB + nf*16 + lr;
            #pragma unroll
            for (int r = 0; r < 4; ++r){
                int row = rowB + mf*16 + hi*4 + r;
                float v = acc[mf][nf][r];
                if constexpr (EPI == 0){
                    float z = v + bias0[col];
                    obf[(size_t)row*256 + col] = f2bf(z);
                } else if constexpr (EPI == 1){
                    float bias = (col < 256) ? bias0[col] : bias1[col - 256];
                    float s = softplus_f(v + bias);
                    obf[(size_t)row*512 + col] = f2bf(s);
                    if (col < 256) o0[(size_t)row*256 + col] = s;
                    else           o1[(size_t)row*256 + col - 256] = s;
                } else {
                    float* dgp = dir ? o1 : o0;
                    const float* bdt = dir ? bias1 : bias0;
                    if (col < 256){
                        dgp[(size_t)row*256 + col] = softplus_f(v + bdt[col]);
                    } else if (col < 272){
                        float* Bp = dir ? oB1 : oB0;
                        Bp[(size_t)row*16 + (col - 256)] = v;
                    } else if (col < 288){
                        float* Cp = dir ? oC1 : oC0;
                        Cp[(size_t)row*16 + (col - 272)] = v;
                    }
                }
            }
        }
    }
}

// Scan pass 1: per-chunk h_end + sum(delta). Thread owns one d, 16 states in regs.
__global__ __launch_bounds__(256)
void k_scan_p1(const float* __restrict__ xc0, const float* __restrict__ dg0,
               const float* __restrict__ B0,  const float* __restrict__ Al0,
               const float* __restrict__ xc1, const float* __restrict__ dg1,
               const float* __restrict__ B1,  const float* __restrict__ Al1,
               float* __restrict__ hend, float* __restrict__ sdl)
{
    __shared__ float sB[CHL*SN];
    int blk = blockIdx.x;                 // 1024 = b(4) * dir(2) * c(128)
    int c = blk & (NCH-1); int dir = (blk>>7) & 1; int b = blk>>8;
    const float* xc   = dir ? xc1 : xc0;
    const float* dg   = dir ? dg1 : dg0;
    const float* Bg   = dir ? B1  : B0;
    const float* Alog = dir ? Al1 : Al0;
    int d = threadIdx.x;
    #pragma unroll
    for (int k = 0; k < 2; ++k){
        int li = threadIdx.x + k*256;
        int i = li >> 4, n = li & 15;
        int tau = c*CHL + i;
        int t = dir ? (SS-1-tau) : tau;
        sB[li] = Bg[((size_t)b*SS + t)*SN + n];
    }
    float A[SN];
    #pragma unroll
    for (int k = 0; k < 4; ++k){
        float4 al = *(const float4*)(Alog + d*SN + k*4);
        A[k*4+0] = -__expf(al.x); A[k*4+1] = -__expf(al.y);
        A[k*4+2] = -__expf(al.z); A[k*4+3] = -__expf(al.w);
    }
    __syncthreads();
    int t0 = dir ? (SS-1 - c*CHL) : (c*CHL);
    const float* pd = dg + ((size_t)b*SS + t0)*SD + d;
    const float* px = xc + ((size_t)b*SS + t0)*SD + d;
    int stride = dir ? -SD : SD;
    float h[SN];
    #pragma unroll
    for (int n = 0; n < SN; ++n) h[n] = 0.f;
    float sumdl = 0.f;
    float dl = *pd, xv = *px;
    for (int i = 0; i < CHL; ++i){
        float dlN = 0.f, xvN = 0.f;
        if (i+1 < CHL){ pd += stride; px += stride; dlN = *pd; xvN = *px; }
        sumdl += dl;
        float dlx = dl * xv;
        const float4* b4 = (const float4*)&sB[i*SN];
        #pragma unroll
        for (int k = 0; k < 4; ++k){
            float4 bb = b4[k];
            h[k*4+0] = fmaf(__expf(dl*A[k*4+0]), h[k*4+0], bb.x*dlx);
            h[k*4+1] = fmaf(__expf(dl*A[k*4+1]), h[k*4+1], bb.y*dlx);
            h[k*4+2] = fmaf(__expf(dl*A[k*4+2]), h[k*4+2], bb.z*dlx);
            h[k*4+3] = fmaf(__expf(dl*A[k*4+3]), h[k*4+3], bb.w*dlx);
        }
        dl = dlN; xv = xvN;
    }
    size_t base = (((size_t)(b*2+dir)*NCH + c)*SD + d)*SN;
    #pragma unroll
    for (int k = 0; k < 4; ++k)
        *(float4*)(hend + base + k*4) = make_float4(h[k*4+0],h[k*4+1],h[k*4+2],h[k*4+3]);
    sdl[((size_t)(b*2+dir)*NCH + c)*SD + d] = sumdl;
}

// Chain chunks serially per (b,dir,d,n); in-place turns hend into h_in.
__global__ __launch_bounds__(256)
void k_chain(const float* __restrict__ Al0, const float* __restrict__ Al1,
             float* hend, const float* __restrict__ sdl)
{
    int gidx = blockIdx.x*256 + threadIdx.x;       // 32768
    int n = gidx & 15; int d = (gidx >> 4) & 255; int dirb = gidx >> 12;
    const float* Alog = (dirb & 1) ? Al1 : Al0;
    float A = -__expf(Alog[d*SN + n]);
    float H = 0.f;
    const size_t cs = (size_t)SD*SN;               // 4096
    size_t idx  = (size_t)dirb*NCH*cs + (size_t)d*SN + n;
    size_t sidx = (size_t)dirb*NCH*SD + d;
    float he[4], sd[4];
    #pragma unroll
    for (int k = 0; k < 4; ++k){
        he[k] = hend[idx + (size_t)k*cs];
        sd[k] = sdl[sidx + (size_t)k*SD];
    }
    for (int cg = 0; cg < NCH; cg += 4){
        float heN[4] = {0.f,0.f,0.f,0.f};
        float sdN[4] = {0.f,0.f,0.f,0.f};
        if (cg + 4 < NCH){
            #pragma unroll
            for (int k = 0; k < 4; ++k){
                heN[k] = hend[idx + (size_t)(k+4)*cs];
                sdN[k] = sdl[sidx + (size_t)(k+4)*SD];
            }
        }
        #pragma unroll
        for (int k = 0; k < 4; ++k){
            hend[idx + (size_t)k*cs] = H;           // now holds h_in
            H = fmaf(__expf(A*sd[k]), H, he[k]);
        }
        #pragma unroll
        for (int k = 0; k < 4; ++k){ he[k] = heN[k]; sd[k] = sdN[k]; }
        idx += 4*cs; sidx += 4*SD;
    }
}

// Scan pass 2: recompute with h_in, emit y (aliases the xc buffer).
__global__ __launch_bounds__(256)
void k_scan_p2(const float* xc0, const float* __restrict__ dg0,
               const float* __restrict__ B0, const float* __restrict__ C0,
               const float* __restrict__ Al0, const float* __restrict__ Dv0,
               float* y0,
               const float* xc1, const float* __restrict__ dg1,
               const float* __restrict__ B1, const float* __restrict__ C1,
               const float* __restrict__ Al1, const float* __restrict__ Dv1,
               float* y1,
               const float* __restrict__ hin)
{
    __shared__ float sB[CHL*SN];
    __shared__ float sC[CHL*SN];
    int blk = blockIdx.x;
    int c = blk & (NCH-1); int dir = (blk>>7) & 1; int b = blk>>8;
    const float* xc   = dir ? xc1 : xc0;
    const float* dg   = dir ? dg1 : dg0;
    const float* Bg   = dir ? B1  : B0;
    const float* Cg   = dir ? C1  : C0;
    const float* Alog = dir ? Al1 : Al0;
    const float* Dv   = dir ? Dv1 : Dv0;
    float* y          = dir ? y1  : y0;
    int d = threadIdx.x;
    #pragma unroll
    for (int k = 0; k < 2; ++k){
        int li = threadIdx.x + k*256;
        int i = li >> 4, n = li & 15;
        int tau = c*CHL + i;
        int t = dir ? (SS-1-tau) : tau;
        sB[li] = Bg[((size_t)b*SS + t)*SN + n];
        sC[li] = Cg[((size_t)b*SS + t)*SN + n];
    }
    float A[SN];
    #pragma unroll
    for (int k = 0; k < 4; ++k){
        float4 al = *(const float4*)(Alog + d*SN + k*4);
        A[k*4+0] = -__expf(al.x); A[k*4+1] = -__expf(al.y);
        A[k*4+2] = -__expf(al.z); A[k*4+3] = -__expf(al.w);
    }
    float h[SN];
    {
        size_t base = (((size_t)(b*2+dir)*NCH + c)*SD + d)*SN;
        #pragma unroll
        for (int k = 0; k < 4; ++k){
            float4 hv = *(const float4*)(hin + base + k*4);
            h[k*4+0]=hv.x; h[k*4+1]=hv.y; h[k*4+2]=hv.z; h[k*4+3]=hv.w;
        }
    }
    float Dd = Dv[d];
    __syncthreads();
    int t0 = dir ? (SS-1 - c*CHL) : (c*CHL);
    const float* pd = dg + ((size_t)b*SS + t0)*SD + d;
    const float* px = xc + ((size_t)b*SS + t0)*SD + d;
    float* py       = y  + ((size_t)b*SS + t0)*SD + d;
    int stride = dir ? -SD : SD;
    float dl = *pd, xv = *px;
    for (int i = 0; i < CHL; ++i){
        float dlN = 0.f, xvN = 0.f;
        if (i+1 < CHL){ pd += stride; px += stride; dlN = *pd; xvN = *px; }
        float dlx = dl * xv;
        float yv = Dd * xv;
        const float4* b4 = (const float4*)&sB[i*SN];
        const float4* c4 = (const float4*)&sC[i*SN];
        #pragma unroll
        for (int k = 0; k < 4; ++k){
            float4 bb = b4[k];
            float4 cc = c4[k];
            h[k*4+0] = fmaf(__expf(dl*A[k*4+0]), h[k*4+0], bb.x*dlx);
            yv = fmaf(h[k*4+0], cc.x, yv);
            h[k*4+1] = fmaf(__expf(dl*A[k*4+1]), h[k*4+1], bb.y*dlx);
            yv = fmaf(h[k*4+1], cc.y, yv);
            h[k*4+2] = fmaf(__expf(dl*A[k*4+2]), h[k*4+2], bb.z*dlx);
            yv = fmaf(h[k*4+2], cc.z, yv);
            h[k*4+3] = fmaf(__expf(dl*A[k*4+3]), h[k*4+3], bb.w*dlx);
            yv = fmaf(h[k*4+3], cc.w, yv);
        }
        *py = yv; py += stride;
        dl = dlN; xv = xvN;
    }
}

// out = (silu(yf) + silu(yb)) * silu(z1) + x   (z1 read as bf16)
__global__ __launch_bounds__(256)
void k_combine(const float* __restrict__ yf, const float* __restrict__ yb,
               const unsigned short* __restrict__ z1bf, const float* __restrict__ x,
               float* __restrict__ out, int nvec)
{
    int i = blockIdx.x*256 + threadIdx.x;
    if (i < nvec){
        float4 a = ((const float4*)yf)[i];
        float4 bq = ((const float4*)yb)[i];
        ushort4 zu = ((const ushort4*)z1bf)[i];
        float4 xq = ((const float4*)x)[i];
        float4 o;
        o.x = (silu_f(a.x) + silu_f(bq.x)) * silu_f(bf2f(zu.x)) + xq.x;
        o.y = (silu_f(a.y) + silu_f(bq.y)) * silu_f(bf2f(zu.y)) + xq.y;
        o.z = (silu_f(a.z) + silu_f(bq.z)) * silu_f(bf2f(zu.z)) + xq.z;
        o.w = (silu_f(a.w) + silu_f(bq.w)) * silu_f(bf2f(zu.w)) + xq.w;
        ((float4*)out)[i] = o;
    }
}

extern "C" void kernel_launch(void* const* d_in, const int* in_sizes, int n_in,
                              void* d_out, int out_size, void* d_ws, size_t ws_size,
                              hipStream_t stream) {
    const float* x     = (const float*)d_in[0];
    const float* ln_g  = (const float*)d_in[1];
    const float* ln_b  = (const float*)d_in[2];
    const float* Wp    = (const float*)d_in[3];
    const float* bp    = (const float*)d_in[4];
    const float* Wcf   = (const float*)d_in[5];
    const float* bcf   = (const float*)d_in[6];
    const float* Wcb   = (const float*)d_in[7];
    const float* bcb   = (const float*)d_in[8];
    const float* Wdbc_f= (const float*)d_in[9];
    const float* Wdt_f = (const float*)d_in[10];
    const float* bdt_f = (const float*)d_in[11];
    const float* Alog_f= (const float*)d_in[12];
    const float* D_f   = (const float*)d_in[13];
    const float* Wdbc_b= (const float*)d_in[14];
    const float* Wdt_b = (const float*)d_in[15];
    const float* bdt_b = (const float*)d_in[16];
    const float* Alog_b= (const float*)d_in[17];
    const float* D_b   = (const float*)d_in[18];
    float* out = (float*)d_out;

    float* ws = (float*)d_ws;
    const size_t NTOK  = (size_t)SB*SS;           // 16384
    const size_t SZ_BD = NTOK*SD;                 // 4,194,304
    const size_t SZ_BN = NTOK*SN;                 // 262,144
    size_t off = 0;
    float* xcg0  = ws + off; off += SZ_BD;
    float* xcg1  = ws + off; off += SZ_BD;
    float* dg0   = ws + off; off += SZ_BD;
    float* dg1   = ws + off; off += SZ_BD;
    float* Bg0   = ws + off; off += SZ_BN;
    float* Bg1   = ws + off; off += SZ_BN;
    float* Cg0   = ws + off; off += SZ_BN;
    float* Cg1   = ws + off; off += SZ_BN;
    // region A: xnbf + z1bf (bf16). z1bf is LIVE until k_combine — nothing
    // else may alias this region (R3 bug: hend aliased it and clobbered z1bf).
    float* regA  = ws + off; off += SZ_BD;
    unsigned short* xnbf = (unsigned short*)regA;
    unsigned short* z1bf = xnbf + SZ_BD;          // 4M ushorts each = 16MB total
    // region B: xcbf (bf16, dead after k_gemm<2>), then reused as hend by the scan.
    float* regB  = ws + off; off += SZ_BD;
    unsigned short* xcbf = (unsigned short*)regB; // 8M ushorts [16384][512]
    float* hend = regB;                            // written by k_scan_p1 (xcbf dead)
    float* sdl   = ws + off; off += (size_t)8*NCH*SD;      // 262,144
    unsigned short* WpT  = (unsigned short*)(ws + off); off += 65536/2;
    unsigned short* Wc   = (unsigned short*)(ws + off); off += 131072/2;
    unsigned short* G3W  = (unsigned short*)(ws + off); off += 163840/2;
    // y aliases xc (read-then-write per element within the owning thread)
    float* y0 = xcg0;
    float* y1 = xcg1;

    k_prep<<<1408, 256, 0, stream>>>(Wp, Wcf, Wcb, Wdbc_f, Wdt_f, Wdbc_b, Wdt_b,
                                     WpT, Wc, G3W);
    k_ln<<<NRB, 256, 0, stream>>>(x, ln_g, ln_b, xnbf);
    k_gemm<0><<<dim3(4,128,1), 256, 0, stream>>>(xnbf, 256, WpT, bp, nullptr,
        nullptr, nullptr, z1bf, nullptr, nullptr, nullptr, nullptr);
    k_gemm<1><<<dim3(8,128,1), 256, 0, stream>>>(z1bf, 256, Wc, bcf, bcb,
        xcg0, xcg1, xcbf, nullptr, nullptr, nullptr, nullptr);
    k_gemm<2><<<dim3(5,128,2), 256, 0, stream>>>(xcbf, 512, G3W, bdt_f, bdt_b,
        dg0, dg1, nullptr, Bg0, Bg1, Cg0, Cg1);
    k_scan_p1<<<1024, 256, 0, stream>>>(xcg0, dg0, Bg0, Alog_f,
                                        xcg1, dg1, Bg1, Alog_b, hend, sdl);
    k_chain<<<128, 256, 0, stream>>>(Alog_f, Alog_b, hend, sdl);
    k_scan_p2<<<1024, 256, 0, stream>>>(
        xcg0, dg0, Bg0, Cg0, Alog_f, D_f, y0,
        xcg1, dg1, Bg1, Cg1, Alog_b, D_b, y1,
        hend);
    k_combine<<<4096, 256, 0, stream>>>(y0, y1, z1bf, x, out, (int)(SZ_BD/4));
}

// Round 6
// 205.914 us; speedup vs baseline: 2.2749x; 1.0251x over previous
//
#include <hip/hip_runtime.h>
#include <math.h>

#define SB 4
#define SS 4096
#define SD 256
#define SN 16
#define ROWS 16
#define NRB 1024        // 16384 rows / 16
#define NCH 128         // chunks per (b,dir)
#define CHL 32          // chunk length; NCH*CHL = SS

// MFMA GEMM tile
#define BM 128
#define BN 64
#define BK 64
#define LDT 72          // BK + 8 bf16 pad (keeps 16B alignment, kills bank conflicts)

typedef __attribute__((ext_vector_type(8))) short bf16x8;
typedef __attribute__((ext_vector_type(4))) float f32x4;

__device__ __forceinline__ unsigned short f2bf(float f){
    unsigned int u = __float_as_uint(f);
    u += 0x7FFFu + ((u >> 16) & 1u);        // round-to-nearest-even
    return (unsigned short)(u >> 16);
}
__device__ __forceinline__ float bf2f(unsigned short u){
    return __uint_as_float(((unsigned int)u) << 16);
}
__device__ __forceinline__ float softplus_f(float x){
    return fmaxf(x, 0.f) + __logf(1.f + __expf(-fabsf(x)));
}
__device__ __forceinline__ float silu_f(float x){
    return x * __builtin_amdgcn_rcpf(1.f + __expf(-x));
}

// Weight prep: bf16 conversions + Wdelta = Wdbc[:,:16] @ Wdt fold.
__global__ __launch_bounds__(256)
void k_prep(const float* __restrict__ Wp,
            const float* __restrict__ Wcf, const float* __restrict__ Wcb,
            const float* __restrict__ Wdbc0, const float* __restrict__ Wdt0,
            const float* __restrict__ Wdbc1, const float* __restrict__ Wdt1,
            unsigned short* __restrict__ WpT, unsigned short* __restrict__ Wc,
            unsigned short* __restrict__ G3W)
{
    int idx = blockIdx.x*256 + threadIdx.x;
    if (idx < 65536){
        int n = idx >> 8, k = idx & 255;
        WpT[idx] = f2bf(Wp[k*256 + n]);
    } else if (idx < 65536 + 131072){
        int j = idx - 65536;
        Wc[j] = f2bf(j < 65536 ? Wcf[j] : Wcb[j - 65536]);
    } else {
        int j = idx - 196608;               // 0 .. 163839
        int dir = j / 81920; int r = j - dir*81920;
        int n = r >> 8, d = r & 255;
        const float* Wdbc = dir ? Wdbc1 : Wdbc0;
        const float* Wdt  = dir ? Wdt1  : Wdt0;
        float v;
        if (n < 256){
            v = 0.f;
            #pragma unroll
            for (int q = 0; q < 16; ++q)
                v = fmaf(Wdbc[d*48 + q], Wdt[q*256 + n], v);
        } else if (n < 272) v = Wdbc[d*48 + 16 + (n-256)];
        else if (n < 288)   v = Wdbc[d*48 + 32 + (n-272)];
        else                v = 0.f;
        G3W[(size_t)dir*81920 + r] = f2bf(v);
    }
}

// LayerNorm -> bf16
__global__ __launch_bounds__(256)
void k_ln(const float* __restrict__ x, const float* __restrict__ g,
          const float* __restrict__ bln, unsigned short* __restrict__ xnbf){
    int row0 = blockIdx.x * ROWS;
    int tid = threadIdx.x; int w = tid >> 6; int lane = tid & 63;
    #pragma unroll
    for (int rep = 0; rep < 4; ++rep){
        int j = rep*4 + w;
        const float* xr = x + (size_t)(row0 + j)*SD;
        float4 v = *(const float4*)(xr + lane*4);
        float s = v.x + v.y + v.z + v.w;
        #pragma unroll
        for (int off = 32; off; off >>= 1) s += __shfl_xor(s, off, 64);
        float mu = s * (1.f/256.f);
        float d0 = v.x-mu, d1 = v.y-mu, d2 = v.z-mu, d3 = v.w-mu;
        float q = d0*d0 + d1*d1 + d2*d2 + d3*d3;
        #pragma unroll
        for (int off = 32; off; off >>= 1) q += __shfl_xor(q, off, 64);
        float rstd = rsqrtf(q*(1.f/256.f) + 1e-5f);
        float4 gg = *(const float4*)(g + lane*4);
        float4 bb = *(const float4*)(bln + lane*4);
        ushort4 o;
        o.x = f2bf(d0*rstd*gg.x + bb.x);
        o.y = f2bf(d1*rstd*gg.y + bb.y);
        o.z = f2bf(d2*rstd*gg.z + bb.z);
        o.w = f2bf(d3*rstd*gg.w + bb.w);
        *(ushort4*)(xnbf + (size_t)(row0+j)*SD + lane*4) = o;
    }
}

// Tiled MFMA bf16 GEMM: C[M x N] = A[M x lda(slice K=256)] @ Bt^T, Bt is [N][256] bf16.
// 256 threads = 4 waves (2x2), wave tile 64x32, 16x16x32 frags.
// SINGLE LDS buffer + register prefetch of next K-tile (R5: dbuf halved
// occupancy to 2 blocks/CU and bought no overlap — regs already pipeline).
template<int EPI>
__global__ __launch_bounds__(256, 5)
void k_gemm(const unsigned short* __restrict__ A, int lda,
            const unsigned short* __restrict__ Bt,
            const float* __restrict__ bias0, const float* __restrict__ bias1,
            float* __restrict__ o0, float* __restrict__ o1,
            unsigned short* __restrict__ obf,
            float* __restrict__ oB0, float* __restrict__ oB1,
            float* __restrict__ oC0, float* __restrict__ oC1)
{
    __shared__ unsigned short sA[BM][LDT];
    __shared__ unsigned short sB[BN][LDT];
    int ntile = blockIdx.x, mtile = blockIdx.y;
    int dir = (EPI == 2) ? blockIdx.z : 0;
    int row0 = mtile * BM;
    int col0 = ntile * BN;
    const unsigned short* Ap  = A  + (EPI == 2 ? dir*256 : 0);
    const unsigned short* Btp = Bt + (EPI == 2 ? (size_t)dir*81920 : 0);

    int tid = threadIdx.x;
    uint4 ra[4], rb[2];
    auto gload = [&](int kt){
        int k0 = kt * BK;
        #pragma unroll
        for (int i = 0; i < 4; ++i){
            int idx = tid + i*256; int r = idx >> 3, kp = idx & 7;
            ra[i] = *(const uint4*)(Ap + (size_t)(row0 + r)*lda + k0 + kp*8);
        }
        #pragma unroll
        for (int i = 0; i < 2; ++i){
            int idx = tid + i*256; int r = idx >> 3, kp = idx & 7;
            rb[i] = *(const uint4*)(Btp + (size_t)(col0 + r)*256 + k0 + kp*8);
        }
    };
    auto swrite = [&](){
        #pragma unroll
        for (int i = 0; i < 4; ++i){
            int idx = tid + i*256; int r = idx >> 3, kp = idx & 7;
            *(uint4*)&sA[r][kp*8] = ra[i];
        }
        #pragma unroll
        for (int i = 0; i < 2; ++i){
            int idx = tid + i*256; int r = idx >> 3, kp = idx & 7;
            *(uint4*)&sB[r][kp*8] = rb[i];
        }
    };

    gload(0); swrite(); __syncthreads();

    int lane = tid & 63, w = tid >> 6;
    int wr = w >> 1, wc = w & 1;
    int lr = lane & 15, hi = lane >> 4;

    f32x4 acc[4][2];
    #pragma unroll
    for (int mf = 0; mf < 4; ++mf)
        #pragma unroll
        for (int nf = 0; nf < 2; ++nf)
            acc[mf][nf] = f32x4{0.f, 0.f, 0.f, 0.f};

    for (int kt = 0; kt < 4; ++kt){
        if (kt < 3) gload(kt + 1);          // next tile -> regs, in flight
        #pragma unroll
        for (int kk = 0; kk < BK; kk += 32){
            bf16x8 af[4], bfr[2];
            #pragma unroll
            for (int mf = 0; mf < 4; ++mf)
                af[mf] = *(const bf16x8*)&sA[wr*64 + mf*16 + lr][kk + hi*8];
            #pragma unroll
            for (int nf = 0; nf < 2; ++nf)
                bfr[nf] = *(const bf16x8*)&sB[wc*32 + nf*16 + lr][kk + hi*8];
            #pragma unroll
            for (int mf = 0; mf < 4; ++mf)
                #pragma unroll
                for (int nf = 0; nf < 2; ++nf)
                    acc[mf][nf] = __builtin_amdgcn_mfma_f32_16x16x32_bf16(
                        af[mf], bfr[nf], acc[mf][nf], 0, 0, 0);
        }
        if (kt < 3){
            __syncthreads();                // all reads of sA/sB done
            swrite();
            __syncthreads();                // new tile visible
        }
    }

    // epilogue
    int colB = col0 + wc*32;
    int rowB = row0 + wr*64;
    #pragma unroll
    for (int mf = 0; mf < 4; ++mf){
        #pragma unroll
        for (int nf = 0; nf < 2; ++nf){
            int col = colB + nf*16 + lr;
            #pragma unroll
            for (int r = 0; r < 4; ++r){
                int row = rowB + mf*16 + hi*4 + r;
                float v = acc[mf][nf][r];
                if constexpr (EPI == 0){
                    float z = v + bias0[col];
                    obf[(size_t)row*256 + col] = f2bf(z);
                } else if constexpr (EPI == 1){
                    float bias = (col < 256) ? bias0[col] : bias1[col - 256];
                    float s = softplus_f(v + bias);
                    obf[(size_t)row*512 + col] = f2bf(s);
                    if (col < 256) o0[(size_t)row*256 + col] = s;
                    else           o1[(size_t)row*256 + col - 256] = s;
                } else {
                    float* dgp = dir ? o1 : o0;
                    const float* bdt = dir ? bias1 : bias0;
                    if (col < 256){
                        dgp[(size_t)row*256 + col] = softplus_f(v + bdt[col]);
                    } else if (col < 272){
                        float* Bp = dir ? oB1 : oB0;
                        Bp[(size_t)row*16 + (col - 256)] = v;
                    } else if (col < 288){
                        float* Cp = dir ? oC1 : oC0;
                        Cp[(size_t)row*16 + (col - 272)] = v;
                    }
                }
            }
        }
    }
}

// Scan pass 1: per-chunk h_end + sum(delta). Thread owns one d, 16 states in regs.
__global__ __launch_bounds__(256)
void k_scan_p1(const float* __restrict__ xc0, const float* __restrict__ dg0,
               const float* __restrict__ B0,  const float* __restrict__ Al0,
               const float* __restrict__ xc1, const float* __restrict__ dg1,
               const float* __restrict__ B1,  const float* __restrict__ Al1,
               float* __restrict__ hend, float* __restrict__ sdl)
{
    __shared__ float sB[CHL*SN];
    int blk = blockIdx.x;                 // 1024 = b(4) * dir(2) * c(128)
    int c = blk & (NCH-1); int dir = (blk>>7) & 1; int b = blk>>8;
    const float* xc   = dir ? xc1 : xc0;
    const float* dg   = dir ? dg1 : dg0;
    const float* Bg   = dir ? B1  : B0;
    const float* Alog = dir ? Al1 : Al0;
    int d = threadIdx.x;
    #pragma unroll
    for (int k = 0; k < 2; ++k){
        int li = threadIdx.x + k*256;
        int i = li >> 4, n = li & 15;
        int tau = c*CHL + i;
        int t = dir ? (SS-1-tau) : tau;
        sB[li] = Bg[((size_t)b*SS + t)*SN + n];
    }
    float A[SN];
    #pragma unroll
    for (int k = 0; k < 4; ++k){
        float4 al = *(const float4*)(Alog + d*SN + k*4);
        A[k*4+0] = -__expf(al.x); A[k*4+1] = -__expf(al.y);
        A[k*4+2] = -__expf(al.z); A[k*4+3] = -__expf(al.w);
    }
    __syncthreads();
    int t0 = dir ? (SS-1 - c*CHL) : (c*CHL);
    const float* pd = dg + ((size_t)b*SS + t0)*SD + d;
    const float* px = xc + ((size_t)b*SS + t0)*SD + d;
    int stride = dir ? -SD : SD;
    float h[SN];
    #pragma unroll
    for (int n = 0; n < SN; ++n) h[n] = 0.f;
    float sumdl = 0.f;
    float dl = *pd, xv = *px;
    for (int i = 0; i < CHL; ++i){
        float dlN = 0.f, xvN = 0.f;
        if (i+1 < CHL){ pd += stride; px += stride; dlN = *pd; xvN = *px; }
        sumdl += dl;
        float dlx = dl * xv;
        const float4* b4 = (const float4*)&sB[i*SN];
        #pragma unroll
        for (int k = 0; k < 4; ++k){
            float4 bb = b4[k];
            h[k*4+0] = fmaf(__expf(dl*A[k*4+0]), h[k*4+0], bb.x*dlx);
            h[k*4+1] = fmaf(__expf(dl*A[k*4+1]), h[k*4+1], bb.y*dlx);
            h[k*4+2] = fmaf(__expf(dl*A[k*4+2]), h[k*4+2], bb.z*dlx);
            h[k*4+3] = fmaf(__expf(dl*A[k*4+3]), h[k*4+3], bb.w*dlx);
        }
        dl = dlN; xv = xvN;
    }
    size_t base = (((size_t)(b*2+dir)*NCH + c)*SD + d)*SN;
    #pragma unroll
    for (int k = 0; k < 4; ++k)
        *(float4*)(hend + base + k*4) = make_float4(h[k*4+0],h[k*4+1],h[k*4+2],h[k*4+3]);
    sdl[((size_t)(b*2+dir)*NCH + c)*SD + d] = sumdl;
}

// Chain chunks serially per (b,dir,d,n); in-place turns hend into h_in.
__global__ __launch_bounds__(256)
void k_chain(const float* __restrict__ Al0, const float* __restrict__ Al1,
             float* hend, const float* __restrict__ sdl)
{
    int gidx = blockIdx.x*256 + threadIdx.x;       // 32768
    int n = gidx & 15; int d = (gidx >> 4) & 255; int dirb = gidx >> 12;
    const float* Alog = (dirb & 1) ? Al1 : Al0;
    float A = -__expf(Alog[d*SN + n]);
    float H = 0.f;
    const size_t cs = (size_t)SD*SN;               // 4096
    size_t idx  = (size_t)dirb*NCH*cs + (size_t)d*SN + n;
    size_t sidx = (size_t)dirb*NCH*SD + d;
    float he[4], sd[4];
    #pragma unroll
    for (int k = 0; k < 4; ++k){
        he[k] = hend[idx + (size_t)k*cs];
        sd[k] = sdl[sidx + (size_t)k*SD];
    }
    for (int cg = 0; cg < NCH; cg += 4){
        float heN[4] = {0.f,0.f,0.f,0.f};
        float sdN[4] = {0.f,0.f,0.f,0.f};
        if (cg + 4 < NCH){
            #pragma unroll
            for (int k = 0; k < 4; ++k){
                heN[k] = hend[idx + (size_t)(k+4)*cs];
                sdN[k] = sdl[sidx + (size_t)(k+4)*SD];
            }
        }
        #pragma unroll
        for (int k = 0; k < 4; ++k){
            hend[idx + (size_t)k*cs] = H;           // now holds h_in
            H = fmaf(__expf(A*sd[k]), H, he[k]);
        }
        #pragma unroll
        for (int k = 0; k < 4; ++k){ he[k] = heN[k]; sd[k] = sdN[k]; }
        idx += 4*cs; sidx += 4*SD;
    }
}

// Scan pass 2: recompute with h_in, emit y (aliases the xc buffer).
__global__ __launch_bounds__(256)
void k_scan_p2(const float* xc0, const float* __restrict__ dg0,
               const float* __restrict__ B0, const float* __restrict__ C0,
               const float* __restrict__ Al0, const float* __restrict__ Dv0,
               float* y0,
               const float* xc1, const float* __restrict__ dg1,
               const float* __restrict__ B1, const float* __restrict__ C1,
               const float* __restrict__ Al1, const float* __restrict__ Dv1,
               float* y1,
               const float* __restrict__ hin)
{
    __shared__ float sB[CHL*SN];
    __shared__ float sC[CHL*SN];
    int blk = blockIdx.x;
    int c = blk & (NCH-1); int dir = (blk>>7) & 1; int b = blk>>8;
    const float* xc   = dir ? xc1 : xc0;
    const float* dg   = dir ? dg1 : dg0;
    const float* Bg   = dir ? B1  : B0;
    const float* Cg   = dir ? C1  : C0;
    const float* Alog = dir ? Al1 : Al0;
    const float* Dv   = dir ? Dv1 : Dv0;
    float* y          = dir ? y1  : y0;
    int d = threadIdx.x;
    #pragma unroll
    for (int k = 0; k < 2; ++k){
        int li = threadIdx.x + k*256;
        int i = li >> 4, n = li & 15;
        int tau = c*CHL + i;
        int t = dir ? (SS-1-tau) : tau;
        sB[li] = Bg[((size_t)b*SS + t)*SN + n];
        sC[li] = Cg[((size_t)b*SS + t)*SN + n];
    }
    float A[SN];
    #pragma unroll
    for (int k = 0; k < 4; ++k){
        float4 al = *(const float4*)(Alog + d*SN + k*4);
        A[k*4+0] = -__expf(al.x); A[k*4+1] = -__expf(al.y);
        A[k*4+2] = -__expf(al.z); A[k*4+3] = -__expf(al.w);
    }
    float h[SN];
    {
        size_t base = (((size_t)(b*2+dir)*NCH + c)*SD + d)*SN;
        #pragma unroll
        for (int k = 0; k < 4; ++k){
            float4 hv = *(const float4*)(hin + base + k*4);
            h[k*4+0]=hv.x; h[k*4+1]=hv.y; h[k*4+2]=hv.z; h[k*4+3]=hv.w;
        }
    }
    float Dd = Dv[d];
    __syncthreads();
    int t0 = dir ? (SS-1 - c*CHL) : (c*CHL);
    const float* pd = dg + ((size_t)b*SS + t0)*SD + d;
    const float* px = xc + ((size_t)b*SS + t0)*SD + d;
    float* py       = y  + ((size_t)b*SS + t0)*SD + d;
    int stride = dir ? -SD : SD;
    float dl = *pd, xv = *px;
    for (int i = 0; i < CHL; ++i){
        float dlN = 0.f, xvN = 0.f;
        if (i+1 < CHL){ pd += stride; px += stride; dlN = *pd; xvN = *px; }
        float dlx = dl * xv;
        float yv = Dd * xv;
        const float4* b4 = (const float4*)&sB[i*SN];
        const float4* c4 = (const float4*)&sC[i*SN];
        #pragma unroll
        for (int k = 0; k < 4; ++k){
            float4 bb = b4[k];
            float4 cc = c4[k];
            h[k*4+0] = fmaf(__expf(dl*A[k*4+0]), h[k*4+0], bb.x*dlx);
            yv = fmaf(h[k*4+0], cc.x, yv);
            h[k*4+1] = fmaf(__expf(dl*A[k*4+1]), h[k*4+1], bb.y*dlx);
            yv = fmaf(h[k*4+1], cc.y, yv);
            h[k*4+2] = fmaf(__expf(dl*A[k*4+2]), h[k*4+2], bb.z*dlx);
            yv = fmaf(h[k*4+2], cc.z, yv);
            h[k*4+3] = fmaf(__expf(dl*A[k*4+3]), h[k*4+3], bb.w*dlx);
            yv = fmaf(h[k*4+3], cc.w, yv);
        }
        *py = yv; py += stride;
        dl = dlN; xv = xvN;
    }
}

// out = (silu(yf) + silu(yb)) * silu(z1) + x   (z1 read as bf16)
__global__ __launch_bounds__(256)
void k_combine(const float* __restrict__ yf, const float* __restrict__ yb,
               const unsigned short* __restrict__ z1bf, const float* __restrict__ x,
               float* __restrict__ out, int nvec)
{
    int i = blockIdx.x*256 + threadIdx.x;
    if (i < nvec){
        float4 a = ((const float4*)yf)[i];
        float4 bq = ((const float4*)yb)[i];
        ushort4 zu = ((const ushort4*)z1bf)[i];
        float4 xq = ((const float4*)x)[i];
        float4 o;
        o.x = (silu_f(a.x) + silu_f(bq.x)) * silu_f(bf2f(zu.x)) + xq.x;
        o.y = (silu_f(a.y) + silu_f(bq.y)) * silu_f(bf2f(zu.y)) + xq.y;
        o.z = (silu_f(a.z) + silu_f(bq.z)) * silu_f(bf2f(zu.z)) + xq.z;
        o.w = (silu_f(a.w) + silu_f(bq.w)) * silu_f(bf2f(zu.w)) + xq.w;
        ((float4*)out)[i] = o;
    }
}

extern "C" void kernel_launch(void* const* d_in, const int* in_sizes, int n_in,
                              void* d_out, int out_size, void* d_ws, size_t ws_size,
                              hipStream_t stream) {
    const float* x     = (const float*)d_in[0];
    const float* ln_g  = (const float*)d_in[1];
    const float* ln_b  = (const float*)d_in[2];
    const float* Wp    = (const float*)d_in[3];
    const float* bp    = (const float*)d_in[4];
    const float* Wcf   = (const float*)d_in[5];
    const float* bcf   = (const float*)d_in[6];
    const float* Wcb   = (const float*)d_in[7];
    const float* bcb   = (const float*)d_in[8];
    const float* Wdbc_f= (const float*)d_in[9];
    const float* Wdt_f = (const float*)d_in[10];
    const float* bdt_f = (const float*)d_in[11];
    const float* Alog_f= (const float*)d_in[12];
    const float* D_f   = (const float*)d_in[13];
    const float* Wdbc_b= (const float*)d_in[14];
    const float* Wdt_b = (const float*)d_in[15];
    const float* bdt_b = (const float*)d_in[16];
    const float* Alog_b= (const float*)d_in[17];
    const float* D_b   = (const float*)d_in[18];
    float* out = (float*)d_out;

    float* ws = (float*)d_ws;
    const size_t NTOK  = (size_t)SB*SS;           // 16384
    const size_t SZ_BD = NTOK*SD;                 // 4,194,304
    const size_t SZ_BN = NTOK*SN;                 // 262,144
    size_t off = 0;
    float* xcg0  = ws + off; off += SZ_BD;
    float* xcg1  = ws + off; off += SZ_BD;
    float* dg0   = ws + off; off += SZ_BD;
    float* dg1   = ws + off; off += SZ_BD;
    float* Bg0   = ws + off; off += SZ_BN;
    float* Bg1   = ws + off; off += SZ_BN;
    float* Cg0   = ws + off; off += SZ_BN;
    float* Cg1   = ws + off; off += SZ_BN;
    // region A: xnbf + z1bf (bf16). z1bf is LIVE until k_combine — nothing
    // else may alias this region.
    float* regA  = ws + off; off += SZ_BD;
    unsigned short* xnbf = (unsigned short*)regA;
    unsigned short* z1bf = xnbf + SZ_BD;          // 4M ushorts each = 16MB total
    // region B: xcbf (bf16, dead after k_gemm<2>), then reused as hend by the scan.
    float* regB  = ws + off; off += SZ_BD;
    unsigned short* xcbf = (unsigned short*)regB; // 8M ushorts [16384][512]
    float* hend = regB;                            // written by k_scan_p1 (xcbf dead)
    float* sdl   = ws + off; off += (size_t)8*NCH*SD;      // 262,144
    unsigned short* WpT  = (unsigned short*)(ws + off); off += 65536/2;
    unsigned short* Wc   = (unsigned short*)(ws + off); off += 131072/2;
    unsigned short* G3W  = (unsigned short*)(ws + off); off += 163840/2;
    // y aliases xc (read-then-write per element within the owning thread)
    float* y0 = xcg0;
    float* y1 = xcg1;

    k_prep<<<1408, 256, 0, stream>>>(Wp, Wcf, Wcb, Wdbc_f, Wdt_f, Wdbc_b, Wdt_b,
                                     WpT, Wc, G3W);
    k_ln<<<NRB, 256, 0, stream>>>(x, ln_g, ln_b, xnbf);
    k_gemm<0><<<dim3(4,128,1), 256, 0, stream>>>(xnbf, 256, WpT, bp, nullptr,
        nullptr, nullptr, z1bf, nullptr, nullptr, nullptr, nullptr);
    k_gemm<1><<<dim3(8,128,1), 256, 0, stream>>>(z1bf, 256, Wc, bcf, bcb,
        xcg0, xcg1, xcbf, nullptr, nullptr, nullptr, nullptr);
    k_gemm<2><<<dim3(5,128,2), 256, 0, stream>>>(xcbf, 512, G3W, bdt_f, bdt_b,
        dg0, dg1, nullptr, Bg0, Bg1, Cg0, Cg1);
    k_scan_p1<<<1024, 256, 0, stream>>>(xcg0, dg0, Bg0, Alog_f,
                                        xcg1, dg1, Bg1, Alog_b, hend, sdl);
    k_chain<<<128, 256, 0, stream>>>(Alog_f, Alog_b, hend, sdl);
    k_scan_p2<<<1024, 256, 0, stream>>>(
        xcg0, dg0, Bg0, Cg0, Alog_f, D_f, y0,
        xcg1, dg1, Bg1, Cg1, Alog_b, D_b, y1,
        hend);
    k_combine<<<4096, 256, 0, stream>>>(y0, y1, z1bf, x, out, (int)(SZ_BD/4));
}